// Round 12
// baseline (819.522 us; speedup 1.0000x reference)
//
#include <hip/hip_runtime.h>

#define BD 4
#define TD 2048
#define DD 2048
#define DID 4096
#define MD (BD*TD)   // 8192 rows
#define CHK 32       // scan chunks
#define CHL (TD/CHK) // 64 steps/chunk

typedef float f32x4 __attribute__((ext_vector_type(4)));
typedef short s16x8 __attribute__((ext_vector_type(8)));
typedef unsigned short u16;
typedef unsigned short u16x4 __attribute__((ext_vector_type(4)));
typedef unsigned short u16x8 __attribute__((ext_vector_type(8)));

__device__ __forceinline__ float bf2f(u16 u) {
    union { unsigned int i; float f; } v; v.i = ((unsigned int)u) << 16; return v.f;
}
__device__ __forceinline__ u16 f2bf(float f) {
    union { float f; unsigned int i; } v; v.f = f;
    unsigned int r = v.i + 0x7fffu + ((v.i >> 16) & 1u);   // RNE
    return (u16)(r >> 16);
}
__device__ __forceinline__ float sigm(float x) { return 1.f / (1.f + __expf(-x)); }

// Non-volatile register-only MFMA: memory ordering comes from __syncthreads();
// register dataflow orders it vs ds_reads (m97 mechanism).
__device__ __forceinline__ void mfma16(f32x4& acc, s16x8 a, s16x8 b) {
    asm("v_mfma_f32_16x16x32_bf16 %0, %1, %2, %0" : "+v"(acc) : "v"(a), "v"(b));
}

__device__ __forceinline__ void gload16(const u16* g, u16* l) {
    __builtin_amdgcn_global_load_lds((__attribute__((address_space(1))) void*)(g),
                                     (__attribute__((address_space(3))) void*)(l),
                                     16, 0, 0);
}

// ---------------- fused fp32 -> bf16 weight convert ----------------
// dst layout (u16, contiguous in ws), SEG = D*D elems:
//   [W_r/W_in 32-row interleave] 2*SEG : per 128-row block nb:
//       r 0-31 = W_r[nb*64..+32), 32-63 = W_in[nb*64..+32),
//       r 64-95 = W_r[+32..64),   96-127 = W_in[+32..64)
//   [W_i]    SEG      at 2*SEG   (rows 4096..6143 of the stacked mixer B)
//   [W_out]  SEG      at 3*SEG
//   [gate/up 32-row interleave] 4*SEG at 4*SEG   (same scheme)
//   [W_down] 2*SEG    at 8*SEG
__global__ __launch_bounds__(256)
void cvt_all(const float4* __restrict__ sr, const float4* __restrict__ sin_,
             const float4* __restrict__ si, const float4* __restrict__ sout,
             const float4* __restrict__ sg, const float4* __restrict__ su,
             const float4* __restrict__ sd, u16x4* __restrict__ dst, int n4) {
    const int SEG  = DD * DD / 4;   // 1048576 float4
    const int ROWQ = DD / 4;        // 512 float4 per row
    int i = blockIdx.x * blockDim.x + threadIdx.x;
    int stride = gridDim.x * blockDim.x;
    for (; i < n4; i += stride) {
        const float4* s; int off; size_t di;
        if (i < 2 * SEG) {                        // W_r / W_in -> interleave
            int which = i / SEG;                  // 0 = W_r, 1 = W_in
            int jj = i - which * SEG;
            int g = jj / ROWQ, cq = jj - g * ROWQ;
            int nb = g >> 6, ii = g & 63;
            int dr = which == 0 ? nb * 128 + (ii < 32 ? ii : ii + 32)
                                : nb * 128 + (ii < 32 ? ii + 32 : ii + 64);
            s = which ? sin_ : sr; off = jj;
            di = (size_t)dr * ROWQ + cq;
        } else if (i < 3 * SEG) {                 // W_i linear
            s = si; off = i - 2 * SEG; di = i;
        } else if (i < 4 * SEG) {                 // W_out linear
            s = sout; off = i - 3 * SEG; di = i;
        } else if (i < 8 * SEG) {                 // gate/up -> interleave
            int j = i - 4 * SEG;
            int which = j / (2 * SEG);            // 0 gate, 1 up
            int jj = j - which * 2 * SEG;
            int g = jj / ROWQ, cq = jj - g * ROWQ;
            int nb = g >> 6, ii = g & 63;
            int dr = which == 0 ? nb * 128 + (ii < 32 ? ii : ii + 32)
                                : nb * 128 + (ii < 32 ? ii + 32 : ii + 64);
            s = which ? su : sg; off = jj;
            di = (size_t)4 * SEG + (size_t)dr * ROWQ + cq;
        } else {                                  // W_down linear
            s = sd; off = i - 8 * SEG; di = i;
        }
        float4 v = s[off];
        u16x4 o = { f2bf(v.x), f2bf(v.y), f2bf(v.z), f2bf(v.w) };
        dst[di] = o;
    }
}

// ---------------- RMSNorm: fp32 in -> bf16 out ----------------
__global__ __launch_bounds__(256) void rmsnorm_kernel(const float* __restrict__ x,
                                                      const float* __restrict__ w,
                                                      u16* __restrict__ out) {
    const int row = blockIdx.x;
    const int tid = threadIdx.x;
    const float4* x4 = (const float4*)(x + (size_t)row * DD);
    float4 a = x4[tid * 2], b = x4[tid * 2 + 1];
    float s = a.x*a.x + a.y*a.y + a.z*a.z + a.w*a.w
            + b.x*b.x + b.y*b.y + b.z*b.z + b.w*b.w;
#pragma unroll
    for (int off = 32; off >= 1; off >>= 1) s += __shfl_xor(s, off, 64);
    __shared__ float red[4];
    if ((tid & 63) == 0) red[tid >> 6] = s;
    __syncthreads();
    float tot = red[0] + red[1] + red[2] + red[3];
    float rs = rsqrtf(tot * (1.f / DD) + 1e-6f);
    const float4* w4 = (const float4*)w;
    float4 wa = w4[tid * 2], wb = w4[tid * 2 + 1];
    u16x8 o = { f2bf(a.x*rs*wa.x), f2bf(a.y*rs*wa.y), f2bf(a.z*rs*wa.z), f2bf(a.w*rs*wa.w),
                f2bf(b.x*rs*wb.x), f2bf(b.y*rs*wb.y), f2bf(b.z*rs*wb.z), f2bf(b.w*rs*wb.w) };
    *(u16x8*)(out + (size_t)row * DD + tid * 8) = o;
}

// ============ 128x128 tile GEMM, BK=64, C = A(MxK) * B(NxK)^T ============
// Round-8 proven structure: 4 waves (2x2 of 64x64), single-buffered 32 KB LDS,
// __syncthreads ordering, XOR-swizzled rows via pre-swizzled gload SOURCE.
// EPI 1: outf = resid + c (fp32)
// EPI 3: fused GLU (32-row gate/up interleaved B): silu(g)*u -> out0
// EPI 6: merged mixer: bcol<2D -> sigmoid(r+bias0)*xp -> out0 (rx interleave);
//        bcol>=2D -> sigmoid(c+bias1) -> out1 (W_i rows)
template<int EPI>
__global__ __launch_bounds__(256)
void gemm_bt(const u16* __restrict__ A, const u16* __restrict__ Bw,
             int M, int N, int K,
             const float* __restrict__ bias0, const float* __restrict__ bias1,
             const float* resid, float* outf,
             u16* __restrict__ out0, u16* __restrict__ out1, int Dsub) {
    __shared__ __align__(16) u16 lA[128 * 64];   // 16 KB
    __shared__ __align__(16) u16 lB[128 * 64];   // 16 KB
    const int tid  = threadIdx.x;
    const int lane = tid & 63;
    const int wave = tid >> 6;
    const int wr = (wave >> 1) << 6;
    const int wc = (wave & 1) << 6;
    const int brow = blockIdx.x * 128;
    const int bcol = blockIdx.y * 128;

    // staging: 32 rows/issue, 8 chunks/row; source chunk pre-swizzled
    const int srow  = tid >> 3;                    // 0..31
    const int schnk = (tid & 7) ^ (srow & 7);      // inverse-swizzle source
    const size_t soff = (size_t)srow * K + (schnk << 3);
    const u16* gA = A  + (size_t)brow * K + soff;
    const u16* gB = Bw + (size_t)bcol * K + soff;
    u16* lAp = lA + tid * 8;                       // linear dest, lane*16B
    u16* lBp = lB + tid * 8;

    // read-address pieces
    const int fr = lane & 15;
    const int lg = lane >> 4;                      // 0..3
    const int ck0 = ((lg)     ^ (fr & 7)) << 4;    // k-half 0 chunk byte
    const int ck1 = ((4 + lg) ^ (fr & 7)) << 4;    // k-half 1 chunk byte
    const char* lAc = (const char*)lA;
    const char* lBc = (const char*)lB;

    f32x4 acc[4][4];
#pragma unroll
    for (int i = 0; i < 4; ++i)
#pragma unroll
        for (int j = 0; j < 4; ++j)
            acc[i][j] = (f32x4){0.f, 0.f, 0.f, 0.f};

    for (int k0 = 0; k0 < K; k0 += 64) {
#pragma unroll
        for (int s = 0; s < 4; ++s) {
            gload16(gA + k0 + (size_t)s * 32 * K, lAp + s * 2048);
            gload16(gB + k0 + (size_t)s * 32 * K, lBp + s * 2048);
        }
        __syncthreads();
        s16x8 af[4][2], bq[4][2];
#pragma unroll
        for (int i = 0; i < 4; ++i) {
            const int ra = (wr + i * 16 + fr) * 128;
            const int rb = (wc + i * 16 + fr) * 128;
            af[i][0] = *(const s16x8*)(lAc + ra + ck0);
            af[i][1] = *(const s16x8*)(lAc + ra + ck1);
            bq[i][0] = *(const s16x8*)(lBc + rb + ck0);
            bq[i][1] = *(const s16x8*)(lBc + rb + ck1);
        }
#pragma unroll
        for (int h = 0; h < 2; ++h)
#pragma unroll
            for (int i = 0; i < 4; ++i)
#pragma unroll
                for (int j = 0; j < 4; ++j)
                    mfma16(acc[i][j], af[i][h], bq[j][h]);
        __syncthreads();
    }

    // MFMA-write -> VALU-read hazard fence
#pragma unroll
    for (int i = 0; i < 4; ++i)
#pragma unroll
        for (int j = 0; j < 4; ++j)
            asm volatile("s_nop 7" : "+v"(acc[i][j]));

    const int r0 = brow + wr + (lg << 2);

    if (EPI == 3 || (EPI == 6 && bcol < 2 * DD)) {
        // paired epilogue: first acc[i][0..1] pairs with second acc[i][2..3]
        const int nb = bcol >> 7;
        const int cbase = nb * 64 + (wc ? 32 : 0);
#pragma unroll
        for (int i = 0; i < 4; ++i)
#pragma unroll
            for (int j = 0; j < 2; ++j)
#pragma unroll
                for (int e = 0; e < 4; ++e) {
                    const int grow = r0 + i * 16 + e;
                    const int col  = cbase + j * 16 + fr;
                    const float g = acc[i][j][e];
                    const float u = acc[i][j + 2][e];
                    float v;
                    if (EPI == 3) v = g * sigm(g) * u;           // silu(gate)*up
                    else          v = sigm(g + bias0[col]) * u;  // sigmoid(r+br)*xp
                    out0[(size_t)grow * Dsub + col] = f2bf(v);
                }
        return;
    }

    const int c0 = bcol + wc + fr;
#pragma unroll
    for (int i = 0; i < 4; ++i) {
#pragma unroll
        for (int j = 0; j < 4; ++j) {
            const int gcol = c0 + j * 16;
#pragma unroll
            for (int e = 0; e < 4; ++e) {
                const int grow = r0 + i * 16 + e;
                float c = acc[i][j][e];
                if (EPI == 1) {
                    const size_t idx = (size_t)grow * N + gcol;
                    outf[idx] = resid[idx] + c;
                } else {  // EPI == 6, g branch: cols offset by 2*DD
                    const int gc = gcol - 2 * DD;
                    out1[(size_t)grow * Dsub + gc] = f2bf(sigm(c + bias1[gc]));
                }
            }
        }
    }
}

// ================= chunked RG-LRU scan (2 passes, x4 vectorized) =================
// BP = sigmoid(r+b_r)*xp from the EPI6 GEMM; b_t = sc * BP.
// pass 1: per-chunk local scan (h0=0) -> carry[b][k][d]
__global__ __launch_bounds__(256)
void scan_partial(const u16x4* __restrict__ BP4,
                  const float4* __restrict__ ld4, float4* __restrict__ carry4) {
    const int d4 = blockIdx.x * 256 + threadIdx.x;   // channel-group (4 ch)
    const int k = blockIdx.y;
    const int b = blockIdx.z;
    const float4 ld = ld4[d4];
    float a[4], sc[4], h[4];
#pragma unroll
    for (int c = 0; c < 4; ++c) {
        float av = sigm(((const float*)&ld)[c]);
        av = fminf(fmaxf(av, 1e-6f), 1.f - 1e-6f);
        a[c] = av; sc[c] = sqrtf(fmaxf(1.f - av * av, 0.f)); h[c] = 0.f;
    }
    size_t idx = (((size_t)b * TD + (size_t)k * CHL) * DD >> 2) + d4;
#pragma unroll 8
    for (int t = 0; t < CHL; ++t) {
        u16x4 bp = BP4[idx];
#pragma unroll
        for (int c = 0; c < 4; ++c) h[c] = a[c] * h[c] + sc[c] * bf2f(bp[c]);
        idx += DD >> 2;
    }
    float4 o = { h[0], h[1], h[2], h[3] };
    carry4[(((size_t)b * CHK + k) * DD >> 2) + d4] = o;
}

// pass 2: inline carry-prefix (over chunk carries) + final scan; emits hsg, hfin
__global__ __launch_bounds__(256)
void scan_final(const u16x4* __restrict__ BP4, const u16x4* __restrict__ G4,
                const float4* __restrict__ ld4, const float4* __restrict__ state4,
                const float4* __restrict__ carry4,
                u16x4* __restrict__ HSG4, float4* __restrict__ hfin4) {
    const int d4 = blockIdx.x * 256 + threadIdx.x;
    const int k = blockIdx.y;
    const int b = blockIdx.z;
    const float4 ld = ld4[d4];
    float a[4], sc[4], aL[4], h[4];
    const float4 st = state4[((size_t)b * DD >> 2) + d4];
#pragma unroll
    for (int c = 0; c < 4; ++c) {
        float av = sigm(((const float*)&ld)[c]);
        av = fminf(fmaxf(av, 1e-6f), 1.f - 1e-6f);
        a[c] = av; sc[c] = sqrtf(fmaxf(1.f - av * av, 0.f));
        float p = av;
#pragma unroll
        for (int i = 0; i < 6; ++i) p *= p;   // a^64 == a^CHL
        aL[c] = p;
        h[c] = ((const float*)&st)[c];
    }
    // carry prefix: h = carryin for chunk k
    for (int kk = 0; kk < k; ++kk) {
        float4 cv = carry4[(((size_t)b * CHK + kk) * DD >> 2) + d4];
#pragma unroll
        for (int c = 0; c < 4; ++c) h[c] = aL[c] * h[c] + ((const float*)&cv)[c];
    }
    size_t idx = (((size_t)b * TD + (size_t)k * CHL) * DD >> 2) + d4;
#pragma unroll 8
    for (int t = 0; t < CHL; ++t) {
        u16x4 bp = BP4[idx];
        u16x4 gv = G4[idx];
        u16x4 o;
#pragma unroll
        for (int c = 0; c < 4; ++c) {
            h[c] = a[c] * h[c] + sc[c] * bf2f(bp[c]);
            o[c] = f2bf(h[c] * bf2f(gv[c]));
        }
        HSG4[idx] = o;
        idx += DD >> 2;
    }
    if (k == CHK - 1) {
        float4 o = { h[0], h[1], h[2], h[3] };
        hfin4[((size_t)b * DD >> 2) + d4] = o;
    }
}

extern "C" void kernel_launch(void* const* d_in, const int* in_sizes, int n_in,
                              void* d_out, int out_size, void* d_ws, size_t ws_size,
                              hipStream_t stream) {
    const float* x       = (const float*)d_in[0];
    const float* state   = (const float*)d_in[1];
    const float* w_norm1 = (const float*)d_in[2];
    const float* W_in    = (const float*)d_in[3];
    const float* W_r     = (const float*)d_in[4];
    const float* b_r     = (const float*)d_in[5];
    const float* W_i     = (const float*)d_in[6];
    const float* b_i     = (const float*)d_in[7];
    const float* log_dec = (const float*)d_in[8];
    const float* W_out   = (const float*)d_in[9];
    const float* w_norm2 = (const float*)d_in[10];
    const float* W_gate  = (const float*)d_in[11];
    const float* W_up    = (const float*)d_in[12];
    const float* W_down  = (const float*)d_in[13];

    float* out  = (float*)d_out;
    float* hfin = out + (size_t)MD * DD;

    const size_t SEGU = (size_t)DD * DD;                    // u16 elems per D*D
    u16* w_rx    = (u16*)d_ws;                              // [W_r/W_in ilv; W_i] = stacked mixer B
    u16* w_out   = w_rx   + 3 * SEGU;                       // W_out
    u16* w_gu    = w_rx   + 4 * SEGU;                       // [gate/up interleave] 4*SEG
    u16* w_down  = w_rx   + 8 * SEGU;                       // W_down 2*SEG
    u16* bufN    = w_rx   + 10 * SEGU;                      // M*D
    u16* bufBP   = bufN   + (size_t)MD * DD;                // M*D (bP; later act M*DI spans bufBP+bufG)
    u16* bufG    = bufBP  + (size_t)MD * DD;                // M*D
    u16* spare   = bufG   + (size_t)MD * DD;                // spare
    float* carry = (float*)spare;                           // B*CHK*D fp32 (1 MB)

    // 1) fused weight converts (r/in and gate/up 32-row interleaved)
    cvt_all<<<2048, 256, 0, stream>>>((const float4*)W_r, (const float4*)W_in,
                                      (const float4*)W_i, (const float4*)W_out,
                                      (const float4*)W_gate, (const float4*)W_up,
                                      (const float4*)W_down, (u16x4*)w_rx,
                                      (int)(10 * SEGU / 4));

    rmsnorm_kernel<<<MD, 256, 0, stream>>>(x, w_norm1, bufN);

    // merged mixer projections: bP (paired rx) + g (W_i), stacked N=6144
    {
        dim3 g1(MD / 128, (3 * DD) / 128);
        gemm_bt<6><<<g1, 256, 0, stream>>>(bufN, w_rx, MD, 3 * DD, DD,
                                           b_r, b_i, nullptr, nullptr, bufBP, bufG, DD);
    }

    // chunked RG-LRU scan (2 passes, x4 vectorized)
    {
        dim3 gp(DD / 1024, CHK, BD);
        scan_partial<<<gp, 256, 0, stream>>>((const u16x4*)bufBP,
                                             (const float4*)log_dec, (float4*)carry);
        scan_final<<<gp, 256, 0, stream>>>((const u16x4*)bufBP, (const u16x4*)bufG,
                                           (const float4*)log_dec, (const float4*)state,
                                           (const float4*)carry,
                                           (u16x4*)bufN, (float4*)hfin);
    }

    // x2 = x + hsg @ W_out^T
    {
        dim3 g2(MD / 128, DD / 128);
        gemm_bt<1><<<g2, 256, 0, stream>>>(bufN, w_out, MD, DD, DD,
                                           nullptr, nullptr, x, out, nullptr, nullptr, 0);
    }

    rmsnorm_kernel<<<MD, 256, 0, stream>>>(out, w_norm2, bufN);

    // fused gate/up + GLU: stacked N=8192, writes act (M x DI) directly
    {
        dim3 g3(MD / 128, (2 * DID) / 128);
        gemm_bt<3><<<g3, 256, 0, stream>>>(bufN, w_gu, MD, 2 * DID, DD,
                                           nullptr, nullptr, nullptr, nullptr, bufBP, nullptr, DID);
    }

    // out = x2 + act @ W_down^T
    {
        dim3 g4(MD / 128, DD / 128);
        gemm_bt<1><<<g4, 256, 0, stream>>>(bufBP, w_down, MD, DD, DID,
                                           nullptr, nullptr, out, out, nullptr, nullptr, 0);
    }
}

// Round 13
// 773.776 us; speedup vs baseline: 1.0591x; 1.0591x over previous
//
#include <hip/hip_runtime.h>

#define BD 4
#define TD 2048
#define DD 2048
#define DID 4096
#define MD (BD*TD)   // 8192 rows
#define CHK 32       // scan chunks
#define CHL (TD/CHK) // 64 steps/chunk

typedef float f32x4 __attribute__((ext_vector_type(4)));
typedef short s16x8 __attribute__((ext_vector_type(8)));
typedef unsigned short u16;
typedef unsigned short u16x4 __attribute__((ext_vector_type(4)));
typedef unsigned short u16x8 __attribute__((ext_vector_type(8)));

__device__ __forceinline__ float bf2f(u16 u) {
    union { unsigned int i; float f; } v; v.i = ((unsigned int)u) << 16; return v.f;
}
__device__ __forceinline__ u16 f2bf(float f) {
    union { float f; unsigned int i; } v; v.f = f;
    unsigned int r = v.i + 0x7fffu + ((v.i >> 16) & 1u);   // RNE
    return (u16)(r >> 16);
}
__device__ __forceinline__ float sigm(float x) { return 1.f / (1.f + __expf(-x)); }

// Non-volatile register-only MFMA: memory ordering comes from __syncthreads();
// register dataflow orders it vs ds_reads (m97 mechanism).
__device__ __forceinline__ void mfma16(f32x4& acc, s16x8 a, s16x8 b) {
    asm("v_mfma_f32_16x16x32_bf16 %0, %1, %2, %0" : "+v"(acc) : "v"(a), "v"(b));
}

__device__ __forceinline__ void gload16(const u16* g, u16* l) {
    __builtin_amdgcn_global_load_lds((__attribute__((address_space(1))) void*)(g),
                                     (__attribute__((address_space(3))) void*)(l),
                                     16, 0, 0);
}

// ---------------- fused fp32 -> bf16 weight convert ----------------
// dst layout (u16, contiguous in ws), SEG = D*D elems:
//   [W_r/W_in 32-row interleave] 2*SEG : per 128-row block nb:
//       r 0-31 = W_r[nb*64..+32), 32-63 = W_in[nb*64..+32),
//       r 64-95 = W_r[+32..64),   96-127 = W_in[+32..64)
//   [W_i]    SEG      at 2*SEG   (rows 4096..6143 of the stacked mixer B)
//   [W_out]  SEG      at 3*SEG
//   [gate/up 32-row interleave] 4*SEG at 4*SEG   (same scheme)
//   [W_down] 2*SEG    at 8*SEG
__global__ __launch_bounds__(256)
void cvt_all(const float4* __restrict__ sr, const float4* __restrict__ sin_,
             const float4* __restrict__ si, const float4* __restrict__ sout,
             const float4* __restrict__ sg, const float4* __restrict__ su,
             const float4* __restrict__ sd, u16x4* __restrict__ dst, int n4) {
    const int SEG  = DD * DD / 4;   // 1048576 float4
    const int ROWQ = DD / 4;        // 512 float4 per row
    int i = blockIdx.x * blockDim.x + threadIdx.x;
    int stride = gridDim.x * blockDim.x;
    for (; i < n4; i += stride) {
        const float4* s; int off; size_t di;
        if (i < 2 * SEG) {                        // W_r / W_in -> interleave
            int which = i / SEG;                  // 0 = W_r, 1 = W_in
            int jj = i - which * SEG;
            int g = jj / ROWQ, cq = jj - g * ROWQ;
            int nb = g >> 6, ii = g & 63;
            int dr = which == 0 ? nb * 128 + (ii < 32 ? ii : ii + 32)
                                : nb * 128 + (ii < 32 ? ii + 32 : ii + 64);
            s = which ? sin_ : sr; off = jj;
            di = (size_t)dr * ROWQ + cq;
        } else if (i < 3 * SEG) {                 // W_i linear
            s = si; off = i - 2 * SEG; di = i;
        } else if (i < 4 * SEG) {                 // W_out linear
            s = sout; off = i - 3 * SEG; di = i;
        } else if (i < 8 * SEG) {                 // gate/up -> interleave
            int j = i - 4 * SEG;
            int which = j / (2 * SEG);            // 0 gate, 1 up
            int jj = j - which * 2 * SEG;
            int g = jj / ROWQ, cq = jj - g * ROWQ;
            int nb = g >> 6, ii = g & 63;
            int dr = which == 0 ? nb * 128 + (ii < 32 ? ii : ii + 32)
                                : nb * 128 + (ii < 32 ? ii + 32 : ii + 64);
            s = which ? su : sg; off = jj;
            di = (size_t)4 * SEG + (size_t)dr * ROWQ + cq;
        } else {                                  // W_down linear
            s = sd; off = i - 8 * SEG; di = i;
        }
        float4 v = s[off];
        u16x4 o = { f2bf(v.x), f2bf(v.y), f2bf(v.z), f2bf(v.w) };
        dst[di] = o;
    }
}

// ---------------- RMSNorm: fp32 in -> bf16 out ----------------
__global__ __launch_bounds__(256) void rmsnorm_kernel(const float* __restrict__ x,
                                                      const float* __restrict__ w,
                                                      u16* __restrict__ out) {
    const int row = blockIdx.x;
    const int tid = threadIdx.x;
    const float4* x4 = (const float4*)(x + (size_t)row * DD);
    float4 a = x4[tid * 2], b = x4[tid * 2 + 1];
    float s = a.x*a.x + a.y*a.y + a.z*a.z + a.w*a.w
            + b.x*b.x + b.y*b.y + b.z*b.z + b.w*b.w;
#pragma unroll
    for (int off = 32; off >= 1; off >>= 1) s += __shfl_xor(s, off, 64);
    __shared__ float red[4];
    if ((tid & 63) == 0) red[tid >> 6] = s;
    __syncthreads();
    float tot = red[0] + red[1] + red[2] + red[3];
    float rs = rsqrtf(tot * (1.f / DD) + 1e-6f);
    const float4* w4 = (const float4*)w;
    float4 wa = w4[tid * 2], wb = w4[tid * 2 + 1];
    u16x8 o = { f2bf(a.x*rs*wa.x), f2bf(a.y*rs*wa.y), f2bf(a.z*rs*wa.z), f2bf(a.w*rs*wa.w),
                f2bf(b.x*rs*wb.x), f2bf(b.y*rs*wb.y), f2bf(b.z*rs*wb.z), f2bf(b.w*rs*wb.w) };
    *(u16x8*)(out + (size_t)row * DD + tid * 8) = o;
}

// ---------------- RMSNorm: bf16 in -> bf16 out ----------------
__global__ __launch_bounds__(256) void rmsnorm_bf16(const u16* __restrict__ x,
                                                    const float* __restrict__ w,
                                                    u16* __restrict__ out) {
    const int row = blockIdx.x;
    const int tid = threadIdx.x;
    u16x8 v = *(const u16x8*)(x + (size_t)row * DD + tid * 8);
    float f[8];
    float s = 0.f;
#pragma unroll
    for (int c = 0; c < 8; ++c) { f[c] = bf2f(v[c]); s += f[c] * f[c]; }
#pragma unroll
    for (int off = 32; off >= 1; off >>= 1) s += __shfl_xor(s, off, 64);
    __shared__ float red[4];
    if ((tid & 63) == 0) red[tid >> 6] = s;
    __syncthreads();
    float tot = red[0] + red[1] + red[2] + red[3];
    float rs = rsqrtf(tot * (1.f / DD) + 1e-6f);
    const float4* w4 = (const float4*)w;
    float4 wa = w4[tid * 2], wb = w4[tid * 2 + 1];
    u16x8 o = { f2bf(f[0]*rs*wa.x), f2bf(f[1]*rs*wa.y), f2bf(f[2]*rs*wa.z), f2bf(f[3]*rs*wa.w),
                f2bf(f[4]*rs*wb.x), f2bf(f[5]*rs*wb.y), f2bf(f[6]*rs*wb.z), f2bf(f[7]*rs*wb.w) };
    *(u16x8*)(out + (size_t)row * DD + tid * 8) = o;
}

// ============ 128x128 tile GEMM, BK=64, C = A(MxK) * B(NxK)^T ============
// Round-8 proven structure: 4 waves (2x2 of 64x64), single-buffered 32 KB LDS,
// __syncthreads ordering, XOR-swizzled rows via pre-swizzled gload SOURCE.
// EPI 3: fused GLU (32-row gate/up interleaved B): silu(g)*u -> out0
// EPI 6: merged mixer: bcol<2D -> sigmoid(r+bias0)*xp -> out0 (rx interleave);
//        bcol>=2D -> sigmoid(c+bias1) -> out1 (W_i rows)
// EPI 7: out0 = f2bf(resid_fp32 + c)           (x2, bf16)
// EPI 8: outf = bf2f(out1) + c                 (final, fp32; out1 = bf16 resid)
template<int EPI>
__global__ __launch_bounds__(256)
void gemm_bt(const u16* __restrict__ A, const u16* __restrict__ Bw,
             int M, int N, int K,
             const float* __restrict__ bias0, const float* __restrict__ bias1,
             const float* resid, float* outf,
             u16* __restrict__ out0, u16* __restrict__ out1, int Dsub) {
    __shared__ __align__(16) u16 lA[128 * 64];   // 16 KB
    __shared__ __align__(16) u16 lB[128 * 64];   // 16 KB
    const int tid  = threadIdx.x;
    const int lane = tid & 63;
    const int wave = tid >> 6;
    const int wr = (wave >> 1) << 6;
    const int wc = (wave & 1) << 6;
    const int brow = blockIdx.x * 128;
    const int bcol = blockIdx.y * 128;

    // staging: 32 rows/issue, 8 chunks/row; source chunk pre-swizzled
    const int srow  = tid >> 3;                    // 0..31
    const int schnk = (tid & 7) ^ (srow & 7);      // inverse-swizzle source
    const size_t soff = (size_t)srow * K + (schnk << 3);
    const u16* gA = A  + (size_t)brow * K + soff;
    const u16* gB = Bw + (size_t)bcol * K + soff;
    u16* lAp = lA + tid * 8;                       // linear dest, lane*16B
    u16* lBp = lB + tid * 8;

    // read-address pieces
    const int fr = lane & 15;
    const int lg = lane >> 4;                      // 0..3
    const int ck0 = ((lg)     ^ (fr & 7)) << 4;    // k-half 0 chunk byte
    const int ck1 = ((4 + lg) ^ (fr & 7)) << 4;    // k-half 1 chunk byte
    const char* lAc = (const char*)lA;
    const char* lBc = (const char*)lB;

    f32x4 acc[4][4];
#pragma unroll
    for (int i = 0; i < 4; ++i)
#pragma unroll
        for (int j = 0; j < 4; ++j)
            acc[i][j] = (f32x4){0.f, 0.f, 0.f, 0.f};

    for (int k0 = 0; k0 < K; k0 += 64) {
#pragma unroll
        for (int s = 0; s < 4; ++s) {
            gload16(gA + k0 + (size_t)s * 32 * K, lAp + s * 2048);
            gload16(gB + k0 + (size_t)s * 32 * K, lBp + s * 2048);
        }
        __syncthreads();
        s16x8 af[4][2], bq[4][2];
#pragma unroll
        for (int i = 0; i < 4; ++i) {
            const int ra = (wr + i * 16 + fr) * 128;
            const int rb = (wc + i * 16 + fr) * 128;
            af[i][0] = *(const s16x8*)(lAc + ra + ck0);
            af[i][1] = *(const s16x8*)(lAc + ra + ck1);
            bq[i][0] = *(const s16x8*)(lBc + rb + ck0);
            bq[i][1] = *(const s16x8*)(lBc + rb + ck1);
        }
#pragma unroll
        for (int h = 0; h < 2; ++h)
#pragma unroll
            for (int i = 0; i < 4; ++i)
#pragma unroll
                for (int j = 0; j < 4; ++j)
                    mfma16(acc[i][j], af[i][h], bq[j][h]);
        __syncthreads();
    }

    // MFMA-write -> VALU-read hazard fence
#pragma unroll
    for (int i = 0; i < 4; ++i)
#pragma unroll
        for (int j = 0; j < 4; ++j)
            asm volatile("s_nop 7" : "+v"(acc[i][j]));

    const int r0 = brow + wr + (lg << 2);

    if (EPI == 3 || (EPI == 6 && bcol < 2 * DD)) {
        // paired epilogue: first acc[i][0..1] pairs with second acc[i][2..3]
        const int nb = bcol >> 7;
        const int cbase = nb * 64 + (wc ? 32 : 0);
#pragma unroll
        for (int i = 0; i < 4; ++i)
#pragma unroll
            for (int j = 0; j < 2; ++j)
#pragma unroll
                for (int e = 0; e < 4; ++e) {
                    const int grow = r0 + i * 16 + e;
                    const int col  = cbase + j * 16 + fr;
                    const float g = acc[i][j][e];
                    const float u = acc[i][j + 2][e];
                    float v;
                    if (EPI == 3) v = g * sigm(g) * u;           // silu(gate)*up
                    else          v = sigm(g + bias0[col]) * u;  // sigmoid(r+br)*xp
                    out0[(size_t)grow * Dsub + col] = f2bf(v);
                }
        return;
    }

    const int c0 = bcol + wc + fr;
#pragma unroll
    for (int i = 0; i < 4; ++i) {
#pragma unroll
        for (int j = 0; j < 4; ++j) {
            const int gcol = c0 + j * 16;
#pragma unroll
            for (int e = 0; e < 4; ++e) {
                const int grow = r0 + i * 16 + e;
                float c = acc[i][j][e];
                if (EPI == 7) {
                    const size_t idx = (size_t)grow * N + gcol;
                    out0[idx] = f2bf(resid[idx] + c);
                } else if (EPI == 8) {
                    const size_t idx = (size_t)grow * N + gcol;
                    outf[idx] = bf2f(out1[idx]) + c;
                } else {  // EPI == 6, g branch: cols offset by 2*DD
                    const int gc = gcol - 2 * DD;
                    out1[(size_t)grow * Dsub + gc] = f2bf(sigm(c + bias1[gc]));
                }
            }
        }
    }
}

// ================= chunked RG-LRU scan (3 passes, x4 vectorized) =================
// BP = sigmoid(r+b_r)*xp from the EPI6 GEMM; b_t = sc * BP.
__global__ __launch_bounds__(256)
void scan_partial(const u16x4* __restrict__ BP4,
                  const float4* __restrict__ ld4, float4* __restrict__ carry4) {
    const int d4 = blockIdx.x * 256 + threadIdx.x;   // channel-group (4 ch)
    const int k = blockIdx.y;
    const int b = blockIdx.z;
    const float4 ld = ld4[d4];
    float a[4], sc[4], h[4];
#pragma unroll
    for (int c = 0; c < 4; ++c) {
        float av = sigm(((const float*)&ld)[c]);
        av = fminf(fmaxf(av, 1e-6f), 1.f - 1e-6f);
        a[c] = av; sc[c] = sqrtf(fmaxf(1.f - av * av, 0.f)); h[c] = 0.f;
    }
    size_t idx = (((size_t)b * TD + (size_t)k * CHL) * DD >> 2) + d4;
#pragma unroll 8
    for (int t = 0; t < CHL; ++t) {
        u16x4 bp = BP4[idx];
#pragma unroll
        for (int c = 0; c < 4; ++c) h[c] = a[c] * h[c] + sc[c] * bf2f(bp[c]);
        idx += DD >> 2;
    }
    float4 o = { h[0], h[1], h[2], h[3] };
    carry4[(((size_t)b * CHK + k) * DD >> 2) + d4] = o;
}

// exclusive prefix over chunk carries -> carryin; also emits hfin (exact)
__global__ __launch_bounds__(256)
void scan_carry(const float4* __restrict__ state4, const float4* __restrict__ ld4,
                const float4* __restrict__ carry4, float4* __restrict__ carryin4,
                float4* __restrict__ hfin4) {
    const int d4 = blockIdx.x * 256 + threadIdx.x;
    const int b = blockIdx.y;
    const float4 ld = ld4[d4];
    float aL[4], h[4];
    const float4 st = state4[((size_t)b * DD >> 2) + d4];
#pragma unroll
    for (int c = 0; c < 4; ++c) {
        float av = sigm(((const float*)&ld)[c]);
        av = fminf(fmaxf(av, 1e-6f), 1.f - 1e-6f);
        float p = av;
#pragma unroll
        for (int i = 0; i < 6; ++i) p *= p;   // a^64 == a^CHL
        aL[c] = p;
        h[c] = ((const float*)&st)[c];
    }
#pragma unroll
    for (int k = 0; k < CHK; ++k) {
        const size_t ci = (((size_t)b * CHK + k) * DD >> 2) + d4;
        float4 o = { h[0], h[1], h[2], h[3] };
        carryin4[ci] = o;
        float4 cv = carry4[ci];
#pragma unroll
        for (int c = 0; c < 4; ++c) h[c] = aL[c] * h[c] + ((const float*)&cv)[c];
    }
    float4 o = { h[0], h[1], h[2], h[3] };
    hfin4[((size_t)b * DD >> 2) + d4] = o;
}

// final pass: true chunk-entry state; emits hsg
__global__ __launch_bounds__(256)
void scan_final(const u16x4* __restrict__ BP4, const u16x4* __restrict__ G4,
                const float4* __restrict__ ld4, const float4* __restrict__ carryin4,
                u16x4* __restrict__ HSG4) {
    const int d4 = blockIdx.x * 256 + threadIdx.x;
    const int k = blockIdx.y;
    const int b = blockIdx.z;
    const float4 ld = ld4[d4];
    float a[4], sc[4], h[4];
    const float4 ci = carryin4[(((size_t)b * CHK + k) * DD >> 2) + d4];
#pragma unroll
    for (int c = 0; c < 4; ++c) {
        float av = sigm(((const float*)&ld)[c]);
        av = fminf(fmaxf(av, 1e-6f), 1.f - 1e-6f);
        a[c] = av; sc[c] = sqrtf(fmaxf(1.f - av * av, 0.f));
        h[c] = ((const float*)&ci)[c];
    }
    size_t idx = (((size_t)b * TD + (size_t)k * CHL) * DD >> 2) + d4;
#pragma unroll 8
    for (int t = 0; t < CHL; ++t) {
        u16x4 bp = BP4[idx];
        u16x4 gv = G4[idx];
        u16x4 o;
#pragma unroll
        for (int c = 0; c < 4; ++c) {
            h[c] = a[c] * h[c] + sc[c] * bf2f(bp[c]);
            o[c] = f2bf(h[c] * bf2f(gv[c]));
        }
        HSG4[idx] = o;
        idx += DD >> 2;
    }
}

extern "C" void kernel_launch(void* const* d_in, const int* in_sizes, int n_in,
                              void* d_out, int out_size, void* d_ws, size_t ws_size,
                              hipStream_t stream) {
    const float* x       = (const float*)d_in[0];
    const float* state   = (const float*)d_in[1];
    const float* w_norm1 = (const float*)d_in[2];
    const float* W_in    = (const float*)d_in[3];
    const float* W_r     = (const float*)d_in[4];
    const float* b_r     = (const float*)d_in[5];
    const float* W_i     = (const float*)d_in[6];
    const float* b_i     = (const float*)d_in[7];
    const float* log_dec = (const float*)d_in[8];
    const float* W_out   = (const float*)d_in[9];
    const float* w_norm2 = (const float*)d_in[10];
    const float* W_gate  = (const float*)d_in[11];
    const float* W_up    = (const float*)d_in[12];
    const float* W_down  = (const float*)d_in[13];

    float* out  = (float*)d_out;
    float* hfin = out + (size_t)MD * DD;

    const size_t SEGU = (size_t)DD * DD;                    // u16 elems per D*D
    u16* w_rx    = (u16*)d_ws;                              // [W_r/W_in ilv; W_i] = stacked mixer B
    u16* w_out   = w_rx   + 3 * SEGU;                       // W_out
    u16* w_gu    = w_rx   + 4 * SEGU;                       // [gate/up interleave] 4*SEG
    u16* w_down  = w_rx   + 8 * SEGU;                       // W_down 2*SEG
    u16* bufN    = w_rx   + 10 * SEGU;                      // M*D
    u16* bufBP   = bufN   + (size_t)MD * DD;                // M*D (bP; later act M*DI spans bufBP+bufG)
    u16* bufG    = bufBP  + (size_t)MD * DD;                // M*D
    u16* bufX2   = bufG   + (size_t)MD * DD;                // M*D (x2 bf16)
    float* carry   = (float*)(bufX2 + (size_t)MD * DD);     // B*CHK*D fp32 (1 MB)
    float* carryin = carry + (size_t)BD * CHK * DD;         // B*CHK*D fp32 (1 MB)

    // 1) fused weight converts (r/in and gate/up 32-row interleaved)
    cvt_all<<<2048, 256, 0, stream>>>((const float4*)W_r, (const float4*)W_in,
                                      (const float4*)W_i, (const float4*)W_out,
                                      (const float4*)W_gate, (const float4*)W_up,
                                      (const float4*)W_down, (u16x4*)w_rx,
                                      (int)(10 * SEGU / 4));

    rmsnorm_kernel<<<MD, 256, 0, stream>>>(x, w_norm1, bufN);

    // merged mixer projections: bP (paired rx) + g (W_i), stacked N=6144
    {
        dim3 g1(MD / 128, (3 * DD) / 128);
        gemm_bt<6><<<g1, 256, 0, stream>>>(bufN, w_rx, MD, 3 * DD, DD,
                                           b_r, b_i, nullptr, nullptr, bufBP, bufG, DD);
    }

    // chunked RG-LRU scan (3 passes, x4 vectorized)
    {
        dim3 gp(DD / 1024, CHK, BD);
        scan_partial<<<gp, 256, 0, stream>>>((const u16x4*)bufBP,
                                             (const float4*)log_dec, (float4*)carry);
        dim3 gc(DD / 1024, BD);
        scan_carry<<<gc, 256, 0, stream>>>((const float4*)state, (const float4*)log_dec,
                                           (const float4*)carry, (float4*)carryin,
                                           (float4*)hfin);
        scan_final<<<gp, 256, 0, stream>>>((const u16x4*)bufBP, (const u16x4*)bufG,
                                           (const float4*)log_dec, (const float4*)carryin,
                                           (u16x4*)bufN);
    }

    // x2 = x + hsg @ W_out^T  (bf16, never output directly)
    {
        dim3 g2(MD / 128, DD / 128);
        gemm_bt<7><<<g2, 256, 0, stream>>>(bufN, w_out, MD, DD, DD,
                                           nullptr, nullptr, x, nullptr, bufX2, nullptr, 0);
    }

    rmsnorm_bf16<<<MD, 256, 0, stream>>>(bufX2, w_norm2, bufN);

    // fused gate/up + GLU: stacked N=8192, writes act (M x DI) directly
    {
        dim3 g3(MD / 128, (2 * DID) / 128);
        gemm_bt<3><<<g3, 256, 0, stream>>>(bufN, w_gu, MD, 2 * DID, DD,
                                           nullptr, nullptr, nullptr, nullptr, bufBP, nullptr, DID);
    }

    // out = bf2f(x2) + act @ W_down^T  (fp32 final)
    {
        dim3 g4(MD / 128, DD / 128);
        gemm_bt<8><<<g4, 256, 0, stream>>>(bufBP, w_down, MD, DD, DID,
                                           nullptr, nullptr, nullptr, out, nullptr, bufX2, 0);
    }
}

// Round 14
// 749.897 us; speedup vs baseline: 1.0928x; 1.0318x over previous
//
#include <hip/hip_runtime.h>

#define BD 4
#define TD 2048
#define DD 2048
#define DID 4096
#define MD (BD*TD)   // 8192 rows
#define CHK 32       // scan chunks
#define CHL (TD/CHK) // 64 steps/chunk

typedef float f32x4 __attribute__((ext_vector_type(4)));
typedef short s16x8 __attribute__((ext_vector_type(8)));
typedef unsigned short u16;
typedef unsigned short u16x4 __attribute__((ext_vector_type(4)));
typedef unsigned short u16x8 __attribute__((ext_vector_type(8)));

__device__ __forceinline__ float bf2f(u16 u) {
    union { unsigned int i; float f; } v; v.i = ((unsigned int)u) << 16; return v.f;
}
__device__ __forceinline__ u16 f2bf(float f) {
    union { float f; unsigned int i; } v; v.f = f;
    unsigned int r = v.i + 0x7fffu + ((v.i >> 16) & 1u);   // RNE
    return (u16)(r >> 16);
}
__device__ __forceinline__ float sigm(float x) { return 1.f / (1.f + __expf(-x)); }

// Non-volatile register-only MFMA: memory ordering comes from __syncthreads();
// register dataflow orders it vs ds_reads (m97 mechanism).
__device__ __forceinline__ void mfma16(f32x4& acc, s16x8 a, s16x8 b) {
    asm("v_mfma_f32_16x16x32_bf16 %0, %1, %2, %0" : "+v"(acc) : "v"(a), "v"(b));
}

__device__ __forceinline__ void gload16(const u16* g, u16* l) {
    __builtin_amdgcn_global_load_lds((__attribute__((address_space(1))) void*)(g),
                                     (__attribute__((address_space(3))) void*)(l),
                                     16, 0, 0);
}

// ---------------- fused fp32 -> bf16 weight convert ----------------
// dst layout (u16, contiguous in ws), SEG = D*D elems:
//   [W_r/W_in 32-row interleave] 2*SEG : per 128-row block nb:
//       r 0-31 = W_r[nb*64..+32), 32-63 = W_in[nb*64..+32),
//       r 64-95 = W_r[+32..64),   96-127 = W_in[+32..64)
//   [W_i]    SEG      at 2*SEG   (rows 4096..6143 of the stacked mixer B)
//   [W_out]  SEG      at 3*SEG
//   [gate/up 32-row interleave] 4*SEG at 4*SEG   (same scheme)
//   [W_down] 2*SEG    at 8*SEG
__global__ __launch_bounds__(256)
void cvt_all(const float4* __restrict__ sr, const float4* __restrict__ sin_,
             const float4* __restrict__ si, const float4* __restrict__ sout,
             const float4* __restrict__ sg, const float4* __restrict__ su,
             const float4* __restrict__ sd, u16x4* __restrict__ dst, int n4) {
    const int SEG  = DD * DD / 4;   // 1048576 float4
    const int ROWQ = DD / 4;        // 512 float4 per row
    int i = blockIdx.x * blockDim.x + threadIdx.x;
    int stride = gridDim.x * blockDim.x;
    for (; i < n4; i += stride) {
        const float4* s; int off; size_t di;
        if (i < 2 * SEG) {                        // W_r / W_in -> interleave
            int which = i / SEG;                  // 0 = W_r, 1 = W_in
            int jj = i - which * SEG;
            int g = jj / ROWQ, cq = jj - g * ROWQ;
            int nb = g >> 6, ii = g & 63;
            int dr = which == 0 ? nb * 128 + (ii < 32 ? ii : ii + 32)
                                : nb * 128 + (ii < 32 ? ii + 32 : ii + 64);
            s = which ? sin_ : sr; off = jj;
            di = (size_t)dr * ROWQ + cq;
        } else if (i < 3 * SEG) {                 // W_i linear
            s = si; off = i - 2 * SEG; di = i;
        } else if (i < 4 * SEG) {                 // W_out linear
            s = sout; off = i - 3 * SEG; di = i;
        } else if (i < 8 * SEG) {                 // gate/up -> interleave
            int j = i - 4 * SEG;
            int which = j / (2 * SEG);            // 0 gate, 1 up
            int jj = j - which * 2 * SEG;
            int g = jj / ROWQ, cq = jj - g * ROWQ;
            int nb = g >> 6, ii = g & 63;
            int dr = which == 0 ? nb * 128 + (ii < 32 ? ii : ii + 32)
                                : nb * 128 + (ii < 32 ? ii + 32 : ii + 64);
            s = which ? su : sg; off = jj;
            di = (size_t)4 * SEG + (size_t)dr * ROWQ + cq;
        } else {                                  // W_down linear
            s = sd; off = i - 8 * SEG; di = i;
        }
        float4 v = s[off];
        u16x4 o = { f2bf(v.x), f2bf(v.y), f2bf(v.z), f2bf(v.w) };
        dst[di] = o;
    }
}

// ---------------- RMSNorm: fp32 in -> bf16 out ----------------
__global__ __launch_bounds__(256) void rmsnorm_kernel(const float* __restrict__ x,
                                                      const float* __restrict__ w,
                                                      u16* __restrict__ out) {
    const int row = blockIdx.x;
    const int tid = threadIdx.x;
    const float4* x4 = (const float4*)(x + (size_t)row * DD);
    float4 a = x4[tid * 2], b = x4[tid * 2 + 1];
    float s = a.x*a.x + a.y*a.y + a.z*a.z + a.w*a.w
            + b.x*b.x + b.y*b.y + b.z*b.z + b.w*b.w;
#pragma unroll
    for (int off = 32; off >= 1; off >>= 1) s += __shfl_xor(s, off, 64);
    __shared__ float red[4];
    if ((tid & 63) == 0) red[tid >> 6] = s;
    __syncthreads();
    float tot = red[0] + red[1] + red[2] + red[3];
    float rs = rsqrtf(tot * (1.f / DD) + 1e-6f);
    const float4* w4 = (const float4*)w;
    float4 wa = w4[tid * 2], wb = w4[tid * 2 + 1];
    u16x8 o = { f2bf(a.x*rs*wa.x), f2bf(a.y*rs*wa.y), f2bf(a.z*rs*wa.z), f2bf(a.w*rs*wa.w),
                f2bf(b.x*rs*wb.x), f2bf(b.y*rs*wb.y), f2bf(b.z*rs*wb.z), f2bf(b.w*rs*wb.w) };
    *(u16x8*)(out + (size_t)row * DD + tid * 8) = o;
}

// ---------------- RMSNorm: bf16 in -> bf16 out ----------------
__global__ __launch_bounds__(256) void rmsnorm_bf16(const u16* __restrict__ x,
                                                    const float* __restrict__ w,
                                                    u16* __restrict__ out) {
    const int row = blockIdx.x;
    const int tid = threadIdx.x;
    u16x8 v = *(const u16x8*)(x + (size_t)row * DD + tid * 8);
    float f[8];
    float s = 0.f;
#pragma unroll
    for (int c = 0; c < 8; ++c) { f[c] = bf2f(v[c]); s += f[c] * f[c]; }
#pragma unroll
    for (int off = 32; off >= 1; off >>= 1) s += __shfl_xor(s, off, 64);
    __shared__ float red[4];
    if ((tid & 63) == 0) red[tid >> 6] = s;
    __syncthreads();
    float tot = red[0] + red[1] + red[2] + red[3];
    float rs = rsqrtf(tot * (1.f / DD) + 1e-6f);
    const float4* w4 = (const float4*)w;
    float4 wa = w4[tid * 2], wb = w4[tid * 2 + 1];
    u16x8 o = { f2bf(f[0]*rs*wa.x), f2bf(f[1]*rs*wa.y), f2bf(f[2]*rs*wa.z), f2bf(f[3]*rs*wa.w),
                f2bf(f[4]*rs*wb.x), f2bf(f[5]*rs*wb.y), f2bf(f[6]*rs*wb.z), f2bf(f[7]*rs*wb.w) };
    *(u16x8*)(out + (size_t)row * DD + tid * 8) = o;
}

// ============ 256x128 tile GEMM, BK=64, C = A(MxK) * B(NxK)^T ============
// 4 waves, each owning a 128x64 output tile (2 wave-rows x 2 wave-cols).
// Bigger wave tile raises arithmetic intensity per LDS byte: 24 frag-reads
// per lane per K-tile for 1M FLOP/wave (42.7 FLOP/B vs 32 at 64x64) ->
// LDS-service ceiling rises from ~60% to ~80% MfmaUtil. Single-buffered
// 48 KB LDS, __syncthreads ordering, XOR-swizzled rows via pre-swizzled
// gload SOURCE (proven r8 structure). 2 blocks/CU (VGPR-capped, bounds(256,2)).
// EPI 3: fused GLU (32-row gate/up interleaved B): silu(g)*u -> out0
// EPI 6: merged mixer: bcol<2D -> sigmoid(r+bias0)*xp -> out0; else g -> out1
// EPI 7: out0 = f2bf(resid_fp32 + c)    EPI 8: outf = bf2f(out1) + c
template<int EPI>
__global__ __launch_bounds__(256, 2)
void gemm_bt(const u16* __restrict__ A, const u16* __restrict__ Bw,
             int M, int N, int K,
             const float* __restrict__ bias0, const float* __restrict__ bias1,
             const float* resid, float* outf,
             u16* __restrict__ out0, u16* __restrict__ out1, int Dsub) {
    __shared__ __align__(16) u16 lA[256 * 64];   // 32 KB
    __shared__ __align__(16) u16 lB[128 * 64];   // 16 KB
    const int tid  = threadIdx.x;
    const int lane = tid & 63;
    const int wave = tid >> 6;
    const int wr = (wave >> 1) << 7;               // 0 / 128
    const int wc = (wave & 1) << 6;                // 0 / 64
    const int brow = blockIdx.x * 256;
    const int bcol = blockIdx.y * 128;

    // staging: 32 rows/issue, 8 chunks/row; source chunk pre-swizzled
    const int srow  = tid >> 3;                    // 0..31
    const int schnk = (tid & 7) ^ (srow & 7);      // inverse-swizzle source
    const size_t soff = (size_t)srow * K + (schnk << 3);
    const u16* gA = A  + (size_t)brow * K + soff;
    const u16* gB = Bw + (size_t)bcol * K + soff;
    u16* lAp = lA + tid * 8;                       // linear dest, lane*16B
    u16* lBp = lB + tid * 8;

    // read-address pieces
    const int fr = lane & 15;
    const int lg = lane >> 4;                      // 0..3
    const int ck0 = ((lg)     ^ (fr & 7)) << 4;    // k-half 0 chunk byte
    const int ck1 = ((4 + lg) ^ (fr & 7)) << 4;    // k-half 1 chunk byte
    const char* lAc = (const char*)lA;
    const char* lBc = (const char*)lB;

    f32x4 acc[8][4];
#pragma unroll
    for (int i = 0; i < 8; ++i)
#pragma unroll
        for (int j = 0; j < 4; ++j)
            acc[i][j] = (f32x4){0.f, 0.f, 0.f, 0.f};

    for (int k0 = 0; k0 < K; k0 += 64) {
#pragma unroll
        for (int s = 0; s < 8; ++s)
            gload16(gA + k0 + (size_t)s * 32 * K, lAp + s * 2048);
#pragma unroll
        for (int s = 0; s < 4; ++s)
            gload16(gB + k0 + (size_t)s * 32 * K, lBp + s * 2048);
        __syncthreads();
        s16x8 bq[4][2];
#pragma unroll
        for (int j = 0; j < 4; ++j) {
            const int rb = (wc + j * 16 + fr) * 128;
            bq[j][0] = *(const s16x8*)(lBc + rb + ck0);
            bq[j][1] = *(const s16x8*)(lBc + rb + ck1);
        }
#pragma unroll
        for (int i = 0; i < 8; ++i) {
            const int ra = (wr + i * 16 + fr) * 128;
            s16x8 a0 = *(const s16x8*)(lAc + ra + ck0);
            s16x8 a1 = *(const s16x8*)(lAc + ra + ck1);
#pragma unroll
            for (int j = 0; j < 4; ++j) {
                mfma16(acc[i][j], a0, bq[j][0]);
                mfma16(acc[i][j], a1, bq[j][1]);
            }
        }
        __syncthreads();
    }

    // MFMA-write -> VALU-read hazard fence
#pragma unroll
    for (int i = 0; i < 8; ++i)
#pragma unroll
        for (int j = 0; j < 4; ++j)
            asm volatile("s_nop 7" : "+v"(acc[i][j]));

    const int r0 = brow + wr + (lg << 2);

    if (EPI == 3 || (EPI == 6 && bcol < 2 * DD)) {
        // paired epilogue: first acc[i][0..1] pairs with second acc[i][2..3]
        const int nb = bcol >> 7;
        const int cbase = nb * 64 + (wc ? 32 : 0);
#pragma unroll
        for (int i = 0; i < 8; ++i)
#pragma unroll
            for (int j = 0; j < 2; ++j)
#pragma unroll
                for (int e = 0; e < 4; ++e) {
                    const int grow = r0 + i * 16 + e;
                    const int col  = cbase + j * 16 + fr;
                    const float g = acc[i][j][e];
                    const float u = acc[i][j + 2][e];
                    float v;
                    if (EPI == 3) v = g * sigm(g) * u;           // silu(gate)*up
                    else          v = sigm(g + bias0[col]) * u;  // sigmoid(r+br)*xp
                    out0[(size_t)grow * Dsub + col] = f2bf(v);
                }
        return;
    }

    const int c0 = bcol + wc + fr;
#pragma unroll
    for (int i = 0; i < 8; ++i) {
#pragma unroll
        for (int j = 0; j < 4; ++j) {
            const int gcol = c0 + j * 16;
#pragma unroll
            for (int e = 0; e < 4; ++e) {
                const int grow = r0 + i * 16 + e;
                float c = acc[i][j][e];
                if (EPI == 7) {
                    const size_t idx = (size_t)grow * N + gcol;
                    out0[idx] = f2bf(resid[idx] + c);
                } else if (EPI == 8) {
                    const size_t idx = (size_t)grow * N + gcol;
                    outf[idx] = bf2f(out1[idx]) + c;
                } else {  // EPI == 6, g branch: cols offset by 2*DD
                    const int gc = gcol - 2 * DD;
                    out1[(size_t)grow * Dsub + gc] = f2bf(sigm(c + bias1[gc]));
                }
            }
        }
    }
}

// ================= chunked RG-LRU scan (3 passes, x4 vectorized) =================
// BP = sigmoid(r+b_r)*xp from the EPI6 GEMM; b_t = sc * BP.
__global__ __launch_bounds__(256)
void scan_partial(const u16x4* __restrict__ BP4,
                  const float4* __restrict__ ld4, float4* __restrict__ carry4) {
    const int d4 = blockIdx.x * 256 + threadIdx.x;   // channel-group (4 ch)
    const int k = blockIdx.y;
    const int b = blockIdx.z;
    const float4 ld = ld4[d4];
    float a[4], sc[4], h[4];
#pragma unroll
    for (int c = 0; c < 4; ++c) {
        float av = sigm(((const float*)&ld)[c]);
        av = fminf(fmaxf(av, 1e-6f), 1.f - 1e-6f);
        a[c] = av; sc[c] = sqrtf(fmaxf(1.f - av * av, 0.f)); h[c] = 0.f;
    }
    size_t idx = (((size_t)b * TD + (size_t)k * CHL) * DD >> 2) + d4;
#pragma unroll 8
    for (int t = 0; t < CHL; ++t) {
        u16x4 bp = BP4[idx];
#pragma unroll
        for (int c = 0; c < 4; ++c) h[c] = a[c] * h[c] + sc[c] * bf2f(bp[c]);
        idx += DD >> 2;
    }
    float4 o = { h[0], h[1], h[2], h[3] };
    carry4[(((size_t)b * CHK + k) * DD >> 2) + d4] = o;
}

// exclusive prefix over chunk carries -> carryin; also emits hfin (exact)
__global__ __launch_bounds__(256)
void scan_carry(const float4* __restrict__ state4, const float4* __restrict__ ld4,
                const float4* __restrict__ carry4, float4* __restrict__ carryin4,
                float4* __restrict__ hfin4) {
    const int d4 = blockIdx.x * 256 + threadIdx.x;
    const int b = blockIdx.y;
    const float4 ld = ld4[d4];
    float aL[4], h[4];
    const float4 st = state4[((size_t)b * DD >> 2) + d4];
#pragma unroll
    for (int c = 0; c < 4; ++c) {
        float av = sigm(((const float*)&ld)[c]);
        av = fminf(fmaxf(av, 1e-6f), 1.f - 1e-6f);
        float p = av;
#pragma unroll
        for (int i = 0; i < 6; ++i) p *= p;   // a^64 == a^CHL
        aL[c] = p;
        h[c] = ((const float*)&st)[c];
    }
#pragma unroll
    for (int k = 0; k < CHK; ++k) {
        const size_t ci = (((size_t)b * CHK + k) * DD >> 2) + d4;
        float4 o = { h[0], h[1], h[2], h[3] };
        carryin4[ci] = o;
        float4 cv = carry4[ci];
#pragma unroll
        for (int c = 0; c < 4; ++c) h[c] = aL[c] * h[c] + ((const float*)&cv)[c];
    }
    float4 o = { h[0], h[1], h[2], h[3] };
    hfin4[((size_t)b * DD >> 2) + d4] = o;
}

// final pass: true chunk-entry state; emits hsg
__global__ __launch_bounds__(256)
void scan_final(const u16x4* __restrict__ BP4, const u16x4* __restrict__ G4,
                const float4* __restrict__ ld4, const float4* __restrict__ carryin4,
                u16x4* __restrict__ HSG4) {
    const int d4 = blockIdx.x * 256 + threadIdx.x;
    const int k = blockIdx.y;
    const int b = blockIdx.z;
    const float4 ld = ld4[d4];
    float a[4], sc[4], h[4];
    const float4 ci = carryin4[(((size_t)b * CHK + k) * DD >> 2) + d4];
#pragma unroll
    for (int c = 0; c < 4; ++c) {
        float av = sigm(((const float*)&ld)[c]);
        av = fminf(fmaxf(av, 1e-6f), 1.f - 1e-6f);
        a[c] = av; sc[c] = sqrtf(fmaxf(1.f - av * av, 0.f));
        h[c] = ((const float*)&ci)[c];
    }
    size_t idx = (((size_t)b * TD + (size_t)k * CHL) * DD >> 2) + d4;
#pragma unroll 8
    for (int t = 0; t < CHL; ++t) {
        u16x4 bp = BP4[idx];
        u16x4 gv = G4[idx];
        u16x4 o;
#pragma unroll
        for (int c = 0; c < 4; ++c) {
            h[c] = a[c] * h[c] + sc[c] * bf2f(bp[c]);
            o[c] = f2bf(h[c] * bf2f(gv[c]));
        }
        HSG4[idx] = o;
        idx += DD >> 2;
    }
}

extern "C" void kernel_launch(void* const* d_in, const int* in_sizes, int n_in,
                              void* d_out, int out_size, void* d_ws, size_t ws_size,
                              hipStream_t stream) {
    const float* x       = (const float*)d_in[0];
    const float* state   = (const float*)d_in[1];
    const float* w_norm1 = (const float*)d_in[2];
    const float* W_in    = (const float*)d_in[3];
    const float* W_r     = (const float*)d_in[4];
    const float* b_r     = (const float*)d_in[5];
    const float* W_i     = (const float*)d_in[6];
    const float* b_i     = (const float*)d_in[7];
    const float* log_dec = (const float*)d_in[8];
    const float* W_out   = (const float*)d_in[9];
    const float* w_norm2 = (const float*)d_in[10];
    const float* W_gate  = (const float*)d_in[11];
    const float* W_up    = (const float*)d_in[12];
    const float* W_down  = (const float*)d_in[13];

    float* out  = (float*)d_out;
    float* hfin = out + (size_t)MD * DD;

    const size_t SEGU = (size_t)DD * DD;                    // u16 elems per D*D
    u16* w_rx    = (u16*)d_ws;                              // [W_r/W_in ilv; W_i] = stacked mixer B
    u16* w_out   = w_rx   + 3 * SEGU;                       // W_out
    u16* w_gu    = w_rx   + 4 * SEGU;                       // [gate/up interleave] 4*SEG
    u16* w_down  = w_rx   + 8 * SEGU;                       // W_down 2*SEG
    u16* bufN    = w_rx   + 10 * SEGU;                      // M*D
    u16* bufBP   = bufN   + (size_t)MD * DD;                // M*D (bP; later act M*DI spans bufBP+bufG)
    u16* bufG    = bufBP  + (size_t)MD * DD;                // M*D
    u16* bufX2   = bufG   + (size_t)MD * DD;                // M*D (x2 bf16)
    float* carry   = (float*)(bufX2 + (size_t)MD * DD);     // B*CHK*D fp32 (1 MB)
    float* carryin = carry + (size_t)BD * CHK * DD;         // B*CHK*D fp32 (1 MB)

    // 1) fused weight converts (r/in and gate/up 32-row interleaved)
    cvt_all<<<2048, 256, 0, stream>>>((const float4*)W_r, (const float4*)W_in,
                                      (const float4*)W_i, (const float4*)W_out,
                                      (const float4*)W_gate, (const float4*)W_up,
                                      (const float4*)W_down, (u16x4*)w_rx,
                                      (int)(10 * SEGU / 4));

    rmsnorm_kernel<<<MD, 256, 0, stream>>>(x, w_norm1, bufN);

    // merged mixer projections: bP (paired rx) + g (W_i), stacked N=6144
    {
        dim3 g1(MD / 256, (3 * DD) / 128);
        gemm_bt<6><<<g1, 256, 0, stream>>>(bufN, w_rx, MD, 3 * DD, DD,
                                           b_r, b_i, nullptr, nullptr, bufBP, bufG, DD);
    }

    // chunked RG-LRU scan (3 passes, x4 vectorized)
    {
        dim3 gp(DD / 1024, CHK, BD);
        scan_partial<<<gp, 256, 0, stream>>>((const u16x4*)bufBP,
                                             (const float4*)log_dec, (float4*)carry);
        dim3 gc(DD / 1024, BD);
        scan_carry<<<gc, 256, 0, stream>>>((const float4*)state, (const float4*)log_dec,
                                           (const float4*)carry, (float4*)carryin,
                                           (float4*)hfin);
        scan_final<<<gp, 256, 0, stream>>>((const u16x4*)bufBP, (const u16x4*)bufG,
                                           (const float4*)log_dec, (const float4*)carryin,
                                           (u16x4*)bufN);
    }

    // x2 = x + hsg @ W_out^T  (bf16, never output directly)
    {
        dim3 g2(MD / 256, DD / 128);
        gemm_bt<7><<<g2, 256, 0, stream>>>(bufN, w_out, MD, DD, DD,
                                           nullptr, nullptr, x, nullptr, bufX2, nullptr, 0);
    }

    rmsnorm_bf16<<<MD, 256, 0, stream>>>(bufX2, w_norm2, bufN);

    // fused gate/up + GLU: stacked N=8192, writes act (M x DI) directly
    {
        dim3 g3(MD / 256, (2 * DID) / 128);
        gemm_bt<3><<<g3, 256, 0, stream>>>(bufN, w_gu, MD, 2 * DID, DD,
                                           nullptr, nullptr, nullptr, nullptr, bufBP, nullptr, DID);
    }

    // out = bf2f(x2) + act @ W_down^T  (fp32 final)
    {
        dim3 g4(MD / 256, DD / 128);
        gemm_bt<8><<<g4, 256, 0, stream>>>(bufBP, w_down, MD, DD, DID,
                                           nullptr, nullptr, nullptr, out, nullptr, bufX2, 0);
    }
}

// Round 15
// 748.054 us; speedup vs baseline: 1.0955x; 1.0025x over previous
//
#include <hip/hip_runtime.h>

#define BD 4
#define TD 2048
#define DD 2048
#define DID 4096
#define MD (BD*TD)   // 8192 rows
#define CHK 32       // scan chunks
#define CHL (TD/CHK) // 64 steps/chunk

typedef float f32x4 __attribute__((ext_vector_type(4)));
typedef short s16x8 __attribute__((ext_vector_type(8)));
typedef unsigned short u16;
typedef unsigned short u16x4 __attribute__((ext_vector_type(4)));
typedef unsigned short u16x8 __attribute__((ext_vector_type(8)));

__device__ __forceinline__ float bf2f(u16 u) {
    union { unsigned int i; float f; } v; v.i = ((unsigned int)u) << 16; return v.f;
}
__device__ __forceinline__ u16 f2bf(float f) {
    union { float f; unsigned int i; } v; v.f = f;
    unsigned int r = v.i + 0x7fffu + ((v.i >> 16) & 1u);   // RNE
    return (u16)(r >> 16);
}
__device__ __forceinline__ float sigm(float x) { return 1.f / (1.f + __expf(-x)); }

// Non-volatile register-only MFMA: memory ordering comes from __syncthreads();
// register dataflow orders it vs ds_reads (m97 mechanism).
__device__ __forceinline__ void mfma16(f32x4& acc, s16x8 a, s16x8 b) {
    asm("v_mfma_f32_16x16x32_bf16 %0, %1, %2, %0" : "+v"(acc) : "v"(a), "v"(b));
}

__device__ __forceinline__ void gload16(const u16* g, u16* l) {
    __builtin_amdgcn_global_load_lds((__attribute__((address_space(1))) void*)(g),
                                     (__attribute__((address_space(3))) void*)(l),
                                     16, 0, 0);
}

// ---------------- fused fp32 -> bf16 weight convert ----------------
// dst layout (u16, contiguous in ws), SEG = D*D elems:
//   [W_r/W_in 32-row interleave] 2*SEG : per 128-row block nb:
//       r 0-31 = W_r[nb*64..+32), 32-63 = W_in[nb*64..+32),
//       r 64-95 = W_r[+32..64),   96-127 = W_in[+32..64)
//   [W_i]    SEG      at 2*SEG   (rows 4096..6143 of the stacked mixer B)
//   [W_out]  SEG      at 3*SEG
//   [gate/up 32-row interleave] 4*SEG at 4*SEG   (same scheme)
//   [W_down] 2*SEG    at 8*SEG
__global__ __launch_bounds__(256)
void cvt_all(const float4* __restrict__ sr, const float4* __restrict__ sin_,
             const float4* __restrict__ si, const float4* __restrict__ sout,
             const float4* __restrict__ sg, const float4* __restrict__ su,
             const float4* __restrict__ sd, u16x4* __restrict__ dst, int n4) {
    const int SEG  = DD * DD / 4;   // 1048576 float4
    const int ROWQ = DD / 4;        // 512 float4 per row
    int i = blockIdx.x * blockDim.x + threadIdx.x;
    int stride = gridDim.x * blockDim.x;
    for (; i < n4; i += stride) {
        const float4* s; int off; size_t di;
        if (i < 2 * SEG) {                        // W_r / W_in -> interleave
            int which = i / SEG;                  // 0 = W_r, 1 = W_in
            int jj = i - which * SEG;
            int g = jj / ROWQ, cq = jj - g * ROWQ;
            int nb = g >> 6, ii = g & 63;
            int dr = which == 0 ? nb * 128 + (ii < 32 ? ii : ii + 32)
                                : nb * 128 + (ii < 32 ? ii + 32 : ii + 64);
            s = which ? sin_ : sr; off = jj;
            di = (size_t)dr * ROWQ + cq;
        } else if (i < 3 * SEG) {                 // W_i linear
            s = si; off = i - 2 * SEG; di = i;
        } else if (i < 4 * SEG) {                 // W_out linear
            s = sout; off = i - 3 * SEG; di = i;
        } else if (i < 8 * SEG) {                 // gate/up -> interleave
            int j = i - 4 * SEG;
            int which = j / (2 * SEG);            // 0 gate, 1 up
            int jj = j - which * 2 * SEG;
            int g = jj / ROWQ, cq = jj - g * ROWQ;
            int nb = g >> 6, ii = g & 63;
            int dr = which == 0 ? nb * 128 + (ii < 32 ? ii : ii + 32)
                                : nb * 128 + (ii < 32 ? ii + 32 : ii + 64);
            s = which ? su : sg; off = jj;
            di = (size_t)4 * SEG + (size_t)dr * ROWQ + cq;
        } else {                                  // W_down linear
            s = sd; off = i - 8 * SEG; di = i;
        }
        float4 v = s[off];
        u16x4 o = { f2bf(v.x), f2bf(v.y), f2bf(v.z), f2bf(v.w) };
        dst[di] = o;
    }
}

// ---------------- RMSNorm: fp32 in -> bf16 out ----------------
__global__ __launch_bounds__(256) void rmsnorm_kernel(const float* __restrict__ x,
                                                      const float* __restrict__ w,
                                                      u16* __restrict__ out) {
    const int row = blockIdx.x;
    const int tid = threadIdx.x;
    const float4* x4 = (const float4*)(x + (size_t)row * DD);
    float4 a = x4[tid * 2], b = x4[tid * 2 + 1];
    float s = a.x*a.x + a.y*a.y + a.z*a.z + a.w*a.w
            + b.x*b.x + b.y*b.y + b.z*b.z + b.w*b.w;
#pragma unroll
    for (int off = 32; off >= 1; off >>= 1) s += __shfl_xor(s, off, 64);
    __shared__ float red[4];
    if ((tid & 63) == 0) red[tid >> 6] = s;
    __syncthreads();
    float tot = red[0] + red[1] + red[2] + red[3];
    float rs = rsqrtf(tot * (1.f / DD) + 1e-6f);
    const float4* w4 = (const float4*)w;
    float4 wa = w4[tid * 2], wb = w4[tid * 2 + 1];
    u16x8 o = { f2bf(a.x*rs*wa.x), f2bf(a.y*rs*wa.y), f2bf(a.z*rs*wa.z), f2bf(a.w*rs*wa.w),
                f2bf(b.x*rs*wb.x), f2bf(b.y*rs*wb.y), f2bf(b.z*rs*wb.z), f2bf(b.w*rs*wb.w) };
    *(u16x8*)(out + (size_t)row * DD + tid * 8) = o;
}

// ---------------- RMSNorm: bf16 in -> bf16 out ----------------
__global__ __launch_bounds__(256) void rmsnorm_bf16(const u16* __restrict__ x,
                                                    const float* __restrict__ w,
                                                    u16* __restrict__ out) {
    const int row = blockIdx.x;
    const int tid = threadIdx.x;
    u16x8 v = *(const u16x8*)(x + (size_t)row * DD + tid * 8);
    float f[8];
    float s = 0.f;
#pragma unroll
    for (int c = 0; c < 8; ++c) { f[c] = bf2f(v[c]); s += f[c] * f[c]; }
#pragma unroll
    for (int off = 32; off >= 1; off >>= 1) s += __shfl_xor(s, off, 64);
    __shared__ float red[4];
    if ((tid & 63) == 0) red[tid >> 6] = s;
    __syncthreads();
    float tot = red[0] + red[1] + red[2] + red[3];
    float rs = rsqrtf(tot * (1.f / DD) + 1e-6f);
    const float4* w4 = (const float4*)w;
    float4 wa = w4[tid * 2], wb = w4[tid * 2 + 1];
    u16x8 o = { f2bf(f[0]*rs*wa.x), f2bf(f[1]*rs*wa.y), f2bf(f[2]*rs*wa.z), f2bf(f[3]*rs*wa.w),
                f2bf(f[4]*rs*wb.x), f2bf(f[5]*rs*wb.y), f2bf(f[6]*rs*wb.z), f2bf(f[7]*rs*wb.w) };
    *(u16x8*)(out + (size_t)row * DD + tid * 8) = o;
}

// ============ 256x128 tile GEMM, BK=64, 8 waves of 64x64, C = A*B^T ============
// 512 threads: 4 row-waves x 2 col-waves, each 64x64 out (acc 4x4 = 64 regs ->
// ~124 total -> 4 waves/SIMD -> 16 waves/CU at 2 blocks). Keeps r14's halved
// HBM panel traffic (256-row blocks) while restoring r8-class occupancy for
// drain hiding. Single-buffered 48 KB LDS, __syncthreads ordering,
// XOR-swizzled rows via pre-swizzled gload SOURCE.
// EPI 3: fused GLU (32-row gate/up interleaved B): silu(g)*u -> out0
// EPI 6: merged mixer: bcol<2D -> sigmoid(r+bias0)*xp -> out0; else g -> out1
// EPI 7: out0 = f2bf(resid_fp32 + c)    EPI 8: outf = bf2f(out1) + c
template<int EPI>
__global__ __launch_bounds__(512, 4)
void gemm_bt(const u16* __restrict__ A, const u16* __restrict__ Bw,
             int M, int N, int K,
             const float* __restrict__ bias0, const float* __restrict__ bias1,
             const float* resid, float* outf,
             u16* __restrict__ out0, u16* __restrict__ out1, int Dsub) {
    __shared__ __align__(16) u16 lA[256 * 64];   // 32 KB
    __shared__ __align__(16) u16 lB[128 * 64];   // 16 KB
    const int tid  = threadIdx.x;
    const int lane = tid & 63;
    const int wave = tid >> 6;                     // 0..7
    const int wr = (wave >> 1) << 6;               // 0/64/128/192
    const int wc = (wave & 1) << 6;                // 0 / 64
    const int brow = blockIdx.x * 256;
    const int bcol = blockIdx.y * 128;

    // staging: 64 rows/issue (512 threads x 16B = 8KB); source chunk pre-swizzled
    const int srow  = tid >> 3;                    // 0..63
    const int schnk = (tid & 7) ^ (srow & 7);      // inverse-swizzle source
    const size_t soff = (size_t)srow * K + (schnk << 3);
    const u16* gA = A  + (size_t)brow * K + soff;
    const u16* gB = Bw + (size_t)bcol * K + soff;
    u16* lAp = lA + tid * 8;                       // linear dest, lane*16B
    u16* lBp = lB + tid * 8;

    // read-address pieces
    const int fr = lane & 15;
    const int lg = lane >> 4;                      // 0..3
    const int ck0 = ((lg)     ^ (fr & 7)) << 4;    // k-half 0 chunk byte
    const int ck1 = ((4 + lg) ^ (fr & 7)) << 4;    // k-half 1 chunk byte
    const char* lAc = (const char*)lA;
    const char* lBc = (const char*)lB;

    f32x4 acc[4][4];
#pragma unroll
    for (int i = 0; i < 4; ++i)
#pragma unroll
        for (int j = 0; j < 4; ++j)
            acc[i][j] = (f32x4){0.f, 0.f, 0.f, 0.f};

    for (int k0 = 0; k0 < K; k0 += 64) {
#pragma unroll
        for (int s = 0; s < 4; ++s)
            gload16(gA + k0 + (size_t)s * 64 * K, lAp + s * 4096);
#pragma unroll
        for (int s = 0; s < 2; ++s)
            gload16(gB + k0 + (size_t)s * 64 * K, lBp + s * 4096);
        __syncthreads();
        s16x8 bq[4][2];
#pragma unroll
        for (int j = 0; j < 4; ++j) {
            const int rb = (wc + j * 16 + fr) * 128;
            bq[j][0] = *(const s16x8*)(lBc + rb + ck0);
            bq[j][1] = *(const s16x8*)(lBc + rb + ck1);
        }
#pragma unroll
        for (int i = 0; i < 4; ++i) {
            const int ra = (wr + i * 16 + fr) * 128;
            s16x8 a0 = *(const s16x8*)(lAc + ra + ck0);
            s16x8 a1 = *(const s16x8*)(lAc + ra + ck1);
#pragma unroll
            for (int j = 0; j < 4; ++j) {
                mfma16(acc[i][j], a0, bq[j][0]);
                mfma16(acc[i][j], a1, bq[j][1]);
            }
        }
        __syncthreads();
    }

    // MFMA-write -> VALU-read hazard fence
#pragma unroll
    for (int i = 0; i < 4; ++i)
#pragma unroll
        for (int j = 0; j < 4; ++j)
            asm volatile("s_nop 7" : "+v"(acc[i][j]));

    const int r0 = brow + wr + (lg << 2);

    if (EPI == 3 || (EPI == 6 && bcol < 2 * DD)) {
        // paired epilogue: first acc[i][0..1] pairs with second acc[i][2..3]
        const int nb = bcol >> 7;
        const int cbase = nb * 64 + (wc ? 32 : 0);
#pragma unroll
        for (int i = 0; i < 4; ++i)
#pragma unroll
            for (int j = 0; j < 2; ++j)
#pragma unroll
                for (int e = 0; e < 4; ++e) {
                    const int grow = r0 + i * 16 + e;
                    const int col  = cbase + j * 16 + fr;
                    const float g = acc[i][j][e];
                    const float u = acc[i][j + 2][e];
                    float v;
                    if (EPI == 3) v = g * sigm(g) * u;           // silu(gate)*up
                    else          v = sigm(g + bias0[col]) * u;  // sigmoid(r+br)*xp
                    out0[(size_t)grow * Dsub + col] = f2bf(v);
                }
        return;
    }

    const int c0 = bcol + wc + fr;
#pragma unroll
    for (int i = 0; i < 4; ++i) {
#pragma unroll
        for (int j = 0; j < 4; ++j) {
            const int gcol = c0 + j * 16;
#pragma unroll
            for (int e = 0; e < 4; ++e) {
                const int grow = r0 + i * 16 + e;
                float c = acc[i][j][e];
                if (EPI == 7) {
                    const size_t idx = (size_t)grow * N + gcol;
                    out0[idx] = f2bf(resid[idx] + c);
                } else if (EPI == 8) {
                    const size_t idx = (size_t)grow * N + gcol;
                    outf[idx] = bf2f(out1[idx]) + c;
                } else {  // EPI == 6, g branch: cols offset by 2*DD
                    const int gc = gcol - 2 * DD;
                    out1[(size_t)grow * Dsub + gc] = f2bf(sigm(c + bias1[gc]));
                }
            }
        }
    }
}

// ================= chunked RG-LRU scan (3 passes, x4 vectorized) =================
// BP = sigmoid(r+b_r)*xp from the EPI6 GEMM; b_t = sc * BP.
__global__ __launch_bounds__(256)
void scan_partial(const u16x4* __restrict__ BP4,
                  const float4* __restrict__ ld4, float4* __restrict__ carry4) {
    const int d4 = blockIdx.x * 256 + threadIdx.x;   // channel-group (4 ch)
    const int k = blockIdx.y;
    const int b = blockIdx.z;
    const float4 ld = ld4[d4];
    float a[4], sc[4], h[4];
#pragma unroll
    for (int c = 0; c < 4; ++c) {
        float av = sigm(((const float*)&ld)[c]);
        av = fminf(fmaxf(av, 1e-6f), 1.f - 1e-6f);
        a[c] = av; sc[c] = sqrtf(fmaxf(1.f - av * av, 0.f)); h[c] = 0.f;
    }
    size_t idx = (((size_t)b * TD + (size_t)k * CHL) * DD >> 2) + d4;
#pragma unroll 8
    for (int t = 0; t < CHL; ++t) {
        u16x4 bp = BP4[idx];
#pragma unroll
        for (int c = 0; c < 4; ++c) h[c] = a[c] * h[c] + sc[c] * bf2f(bp[c]);
        idx += DD >> 2;
    }
    float4 o = { h[0], h[1], h[2], h[3] };
    carry4[(((size_t)b * CHK + k) * DD >> 2) + d4] = o;
}

// exclusive prefix over chunk carries -> carryin; also emits hfin (exact)
__global__ __launch_bounds__(256)
void scan_carry(const float4* __restrict__ state4, const float4* __restrict__ ld4,
                const float4* __restrict__ carry4, float4* __restrict__ carryin4,
                float4* __restrict__ hfin4) {
    const int d4 = blockIdx.x * 256 + threadIdx.x;
    const int b = blockIdx.y;
    const float4 ld = ld4[d4];
    float aL[4], h[4];
    const float4 st = state4[((size_t)b * DD >> 2) + d4];
#pragma unroll
    for (int c = 0; c < 4; ++c) {
        float av = sigm(((const float*)&ld)[c]);
        av = fminf(fmaxf(av, 1e-6f), 1.f - 1e-6f);
        float p = av;
#pragma unroll
        for (int i = 0; i < 6; ++i) p *= p;   // a^64 == a^CHL
        aL[c] = p;
        h[c] = ((const float*)&st)[c];
    }
#pragma unroll
    for (int k = 0; k < CHK; ++k) {
        const size_t ci = (((size_t)b * CHK + k) * DD >> 2) + d4;
        float4 o = { h[0], h[1], h[2], h[3] };
        carryin4[ci] = o;
        float4 cv = carry4[ci];
#pragma unroll
        for (int c = 0; c < 4; ++c) h[c] = aL[c] * h[c] + ((const float*)&cv)[c];
    }
    float4 o = { h[0], h[1], h[2], h[3] };
    hfin4[((size_t)b * DD >> 2) + d4] = o;
}

// final pass: true chunk-entry state; emits hsg
__global__ __launch_bounds__(256)
void scan_final(const u16x4* __restrict__ BP4, const u16x4* __restrict__ G4,
                const float4* __restrict__ ld4, const float4* __restrict__ carryin4,
                u16x4* __restrict__ HSG4) {
    const int d4 = blockIdx.x * 256 + threadIdx.x;
    const int k = blockIdx.y;
    const int b = blockIdx.z;
    const float4 ld = ld4[d4];
    float a[4], sc[4], h[4];
    const float4 ci = carryin4[(((size_t)b * CHK + k) * DD >> 2) + d4];
#pragma unroll
    for (int c = 0; c < 4; ++c) {
        float av = sigm(((const float*)&ld)[c]);
        av = fminf(fmaxf(av, 1e-6f), 1.f - 1e-6f);
        a[c] = av; sc[c] = sqrtf(fmaxf(1.f - av * av, 0.f));
        h[c] = ((const float*)&ci)[c];
    }
    size_t idx = (((size_t)b * TD + (size_t)k * CHL) * DD >> 2) + d4;
#pragma unroll 8
    for (int t = 0; t < CHL; ++t) {
        u16x4 bp = BP4[idx];
        u16x4 gv = G4[idx];
        u16x4 o;
#pragma unroll
        for (int c = 0; c < 4; ++c) {
            h[c] = a[c] * h[c] + sc[c] * bf2f(bp[c]);
            o[c] = f2bf(h[c] * bf2f(gv[c]));
        }
        HSG4[idx] = o;
        idx += DD >> 2;
    }
}

extern "C" void kernel_launch(void* const* d_in, const int* in_sizes, int n_in,
                              void* d_out, int out_size, void* d_ws, size_t ws_size,
                              hipStream_t stream) {
    const float* x       = (const float*)d_in[0];
    const float* state   = (const float*)d_in[1];
    const float* w_norm1 = (const float*)d_in[2];
    const float* W_in    = (const float*)d_in[3];
    const float* W_r     = (const float*)d_in[4];
    const float* b_r     = (const float*)d_in[5];
    const float* W_i     = (const float*)d_in[6];
    const float* b_i     = (const float*)d_in[7];
    const float* log_dec = (const float*)d_in[8];
    const float* W_out   = (const float*)d_in[9];
    const float* w_norm2 = (const float*)d_in[10];
    const float* W_gate  = (const float*)d_in[11];
    const float* W_up    = (const float*)d_in[12];
    const float* W_down  = (const float*)d_in[13];

    float* out  = (float*)d_out;
    float* hfin = out + (size_t)MD * DD;

    const size_t SEGU = (size_t)DD * DD;                    // u16 elems per D*D
    u16* w_rx    = (u16*)d_ws;                              // [W_r/W_in ilv; W_i] = stacked mixer B
    u16* w_out   = w_rx   + 3 * SEGU;                       // W_out
    u16* w_gu    = w_rx   + 4 * SEGU;                       // [gate/up interleave] 4*SEG
    u16* w_down  = w_rx   + 8 * SEGU;                       // W_down 2*SEG
    u16* bufN    = w_rx   + 10 * SEGU;                      // M*D
    u16* bufBP   = bufN   + (size_t)MD * DD;                // M*D (bP; later act M*DI spans bufBP+bufG)
    u16* bufG    = bufBP  + (size_t)MD * DD;                // M*D
    u16* bufX2   = bufG   + (size_t)MD * DD;                // M*D (x2 bf16)
    float* carry   = (float*)(bufX2 + (size_t)MD * DD);     // B*CHK*D fp32 (1 MB)
    float* carryin = carry + (size_t)BD * CHK * DD;         // B*CHK*D fp32 (1 MB)

    // 1) fused weight converts (r/in and gate/up 32-row interleaved)
    cvt_all<<<2048, 256, 0, stream>>>((const float4*)W_r, (const float4*)W_in,
                                      (const float4*)W_i, (const float4*)W_out,
                                      (const float4*)W_gate, (const float4*)W_up,
                                      (const float4*)W_down, (u16x4*)w_rx,
                                      (int)(10 * SEGU / 4));

    rmsnorm_kernel<<<MD, 256, 0, stream>>>(x, w_norm1, bufN);

    // merged mixer projections: bP (paired rx) + g (W_i), stacked N=6144
    {
        dim3 g1(MD / 256, (3 * DD) / 128);
        gemm_bt<6><<<g1, 512, 0, stream>>>(bufN, w_rx, MD, 3 * DD, DD,
                                           b_r, b_i, nullptr, nullptr, bufBP, bufG, DD);
    }

    // chunked RG-LRU scan (3 passes, x4 vectorized)
    {
        dim3 gp(DD / 1024, CHK, BD);
        scan_partial<<<gp, 256, 0, stream>>>((const u16x4*)bufBP,
                                             (const float4*)log_dec, (float4*)carry);
        dim3 gc(DD / 1024, BD);
        scan_carry<<<gc, 256, 0, stream>>>((const float4*)state, (const float4*)log_dec,
                                           (const float4*)carry, (float4*)carryin,
                                           (float4*)hfin);
        scan_final<<<gp, 256, 0, stream>>>((const u16x4*)bufBP, (const u16x4*)bufG,
                                           (const float4*)log_dec, (const float4*)carryin,
                                           (u16x4*)bufN);
    }

    // x2 = x + hsg @ W_out^T  (bf16, never output directly)
    {
        dim3 g2(MD / 256, DD / 128);
        gemm_bt<7><<<g2, 512, 0, stream>>>(bufN, w_out, MD, DD, DD,
                                           nullptr, nullptr, x, nullptr, bufX2, nullptr, 0);
    }

    rmsnorm_bf16<<<MD, 256, 0, stream>>>(bufX2, w_norm2, bufN);

    // fused gate/up + GLU: stacked N=8192, writes act (M x DI) directly
    {
        dim3 g3(MD / 256, (2 * DID) / 128);
        gemm_bt<3><<<g3, 512, 0, stream>>>(bufN, w_gu, MD, 2 * DID, DD,
                                           nullptr, nullptr, nullptr, nullptr, bufBP, nullptr, DID);
    }

    // out = bf2f(x2) + act @ W_down^T  (fp32 final)
    {
        dim3 g4(MD / 256, DD / 128);
        gemm_bt<8><<<g4, 512, 0, stream>>>(bufBP, w_down, MD, DD, DID,
                                           nullptr, nullptr, nullptr, out, nullptr, bufX2, 0);
    }
}

// Round 17
// 746.066 us; speedup vs baseline: 1.0985x; 1.0027x over previous
//
#include <hip/hip_runtime.h>

#define BD 4
#define TD 2048
#define DD 2048
#define DID 4096
#define MD (BD*TD)   // 8192 rows
#define CHK 32       // scan chunks
#define CHL (TD/CHK) // 64 steps/chunk

typedef float f32x4 __attribute__((ext_vector_type(4)));
typedef short s16x8 __attribute__((ext_vector_type(8)));
typedef unsigned short u16;
typedef unsigned short u16x4 __attribute__((ext_vector_type(4)));
typedef unsigned short u16x8 __attribute__((ext_vector_type(8)));

__device__ __forceinline__ float bf2f(u16 u) {
    union { unsigned int i; float f; } v; v.i = ((unsigned int)u) << 16; return v.f;
}
__device__ __forceinline__ u16 f2bf(float f) {
    union { float f; unsigned int i; } v; v.f = f;
    unsigned int r = v.i + 0x7fffu + ((v.i >> 16) & 1u);   // RNE
    return (u16)(r >> 16);
}
__device__ __forceinline__ float sigm(float x) { return 1.f / (1.f + __expf(-x)); }

// Non-volatile register-only MFMA: memory ordering comes from __syncthreads();
// register dataflow orders it vs ds_reads (m97 mechanism).
__device__ __forceinline__ void mfma16(f32x4& acc, s16x8 a, s16x8 b) {
    asm("v_mfma_f32_16x16x32_bf16 %0, %1, %2, %0" : "+v"(acc) : "v"(a), "v"(b));
}

__device__ __forceinline__ void gload16(const u16* g, u16* l) {
    __builtin_amdgcn_global_load_lds((__attribute__((address_space(1))) void*)(g),
                                     (__attribute__((address_space(3))) void*)(l),
                                     16, 0, 0);
}

// ---------------- fused fp32 -> bf16 weight convert ----------------
// dst layout (u16, contiguous in ws), SEG = D*D elems:
//   [W_r/W_in 32-row interleave] 2*SEG : per 128-row block nb:
//       r 0-31 = W_r[nb*64..+32), 32-63 = W_in[nb*64..+32),
//       r 64-95 = W_r[+32..64),   96-127 = W_in[+32..64)
//   [W_i]    SEG      at 2*SEG   (rows 4096..6143 of the stacked mixer B)
//   [W_out]  SEG      at 3*SEG
//   [gate/up 32-row interleave] 4*SEG at 4*SEG   (same scheme)
//   [W_down] 2*SEG    at 8*SEG
__global__ __launch_bounds__(256)
void cvt_all(const float4* __restrict__ sr, const float4* __restrict__ sin_,
             const float4* __restrict__ si, const float4* __restrict__ sout,
             const float4* __restrict__ sg, const float4* __restrict__ su,
             const float4* __restrict__ sd, u16x4* __restrict__ dst, int n4) {
    const int SEG  = DD * DD / 4;   // 1048576 float4
    const int ROWQ = DD / 4;        // 512 float4 per row
    int i = blockIdx.x * blockDim.x + threadIdx.x;
    int stride = gridDim.x * blockDim.x;
    for (; i < n4; i += stride) {
        const float4* s; int off; size_t di;
        if (i < 2 * SEG) {                        // W_r / W_in -> interleave
            int which = i / SEG;                  // 0 = W_r, 1 = W_in
            int jj = i - which * SEG;
            int g = jj / ROWQ, cq = jj - g * ROWQ;
            int nb = g >> 6, ii = g & 63;
            int dr = which == 0 ? nb * 128 + (ii < 32 ? ii : ii + 32)
                                : nb * 128 + (ii < 32 ? ii + 32 : ii + 64);
            s = which ? sin_ : sr; off = jj;
            di = (size_t)dr * ROWQ + cq;
        } else if (i < 3 * SEG) {                 // W_i linear
            s = si; off = i - 2 * SEG; di = i;
        } else if (i < 4 * SEG) {                 // W_out linear
            s = sout; off = i - 3 * SEG; di = i;
        } else if (i < 8 * SEG) {                 // gate/up -> interleave
            int j = i - 4 * SEG;
            int which = j / (2 * SEG);            // 0 gate, 1 up
            int jj = j - which * 2 * SEG;
            int g = jj / ROWQ, cq = jj - g * ROWQ;
            int nb = g >> 6, ii = g & 63;
            int dr = which == 0 ? nb * 128 + (ii < 32 ? ii : ii + 32)
                                : nb * 128 + (ii < 32 ? ii + 32 : ii + 64);
            s = which ? su : sg; off = jj;
            di = (size_t)4 * SEG + (size_t)dr * ROWQ + cq;
        } else {                                  // W_down linear
            s = sd; off = i - 8 * SEG; di = i;
        }
        float4 v = s[off];
        u16x4 o = { f2bf(v.x), f2bf(v.y), f2bf(v.z), f2bf(v.w) };
        dst[di] = o;
    }
}

// ---------------- RMSNorm: fp32 in -> bf16 out ----------------
__global__ __launch_bounds__(256) void rmsnorm_kernel(const float* __restrict__ x,
                                                      const float* __restrict__ w,
                                                      u16* __restrict__ out) {
    const int row = blockIdx.x;
    const int tid = threadIdx.x;
    const float4* x4 = (const float4*)(x + (size_t)row * DD);
    float4 a = x4[tid * 2], b = x4[tid * 2 + 1];
    float s = a.x*a.x + a.y*a.y + a.z*a.z + a.w*a.w
            + b.x*b.x + b.y*b.y + b.z*b.z + b.w*b.w;
#pragma unroll
    for (int off = 32; off >= 1; off >>= 1) s += __shfl_xor(s, off, 64);
    __shared__ float red[4];
    if ((tid & 63) == 0) red[tid >> 6] = s;
    __syncthreads();
    float tot = red[0] + red[1] + red[2] + red[3];
    float rs = rsqrtf(tot * (1.f / DD) + 1e-6f);
    const float4* w4 = (const float4*)w;
    float4 wa = w4[tid * 2], wb = w4[tid * 2 + 1];
    u16x8 o = { f2bf(a.x*rs*wa.x), f2bf(a.y*rs*wa.y), f2bf(a.z*rs*wa.z), f2bf(a.w*rs*wa.w),
                f2bf(b.x*rs*wb.x), f2bf(b.y*rs*wb.y), f2bf(b.z*rs*wb.z), f2bf(b.w*rs*wb.w) };
    *(u16x8*)(out + (size_t)row * DD + tid * 8) = o;
}

// ---------------- RMSNorm: bf16 in -> bf16 out ----------------
__global__ __launch_bounds__(256) void rmsnorm_bf16(const u16* __restrict__ x,
                                                    const float* __restrict__ w,
                                                    u16* __restrict__ out) {
    const int row = blockIdx.x;
    const int tid = threadIdx.x;
    u16x8 v = *(const u16x8*)(x + (size_t)row * DD + tid * 8);
    float f[8];
    float s = 0.f;
#pragma unroll
    for (int c = 0; c < 8; ++c) { f[c] = bf2f(v[c]); s += f[c] * f[c]; }
#pragma unroll
    for (int off = 32; off >= 1; off >>= 1) s += __shfl_xor(s, off, 64);
    __shared__ float red[4];
    if ((tid & 63) == 0) red[tid >> 6] = s;
    __syncthreads();
    float tot = red[0] + red[1] + red[2] + red[3];
    float rs = rsqrtf(tot * (1.f / DD) + 1e-6f);
    const float4* w4 = (const float4*)w;
    float4 wa = w4[tid * 2], wb = w4[tid * 2 + 1];
    u16x8 o = { f2bf(f[0]*rs*wa.x), f2bf(f[1]*rs*wa.y), f2bf(f[2]*rs*wa.z), f2bf(f[3]*rs*wa.w),
                f2bf(f[4]*rs*wb.x), f2bf(f[5]*rs*wb.y), f2bf(f[6]*rs*wb.z), f2bf(f[7]*rs*wb.w) };
    *(u16x8*)(out + (size_t)row * DD + tid * 8) = o;
}

// ============ 256x128 tile GEMM, BK=64, 8 waves of 64x64, C = A*B^T ============
// 512 threads: 4 row-waves x 2 col-waves, each 64x64 out (acc 4x4 = 64 regs ->
// 4 waves/SIMD -> 16 waves/CU at 2 blocks). 256-row blocks halve HBM panel
// traffic; single-buffered 48 KB LDS, __syncthreads ordering, XOR-swizzled
// rows via pre-swizzled gload SOURCE (proven r8/r15 structure).
// EPI 3: fused GLU (32-row gate/up interleaved B): silu(g)*u -> out0
// EPI 6: merged mixer: bcol<2D -> sigmoid(r+bias0)*xp -> out0; else g -> out1
// EPI 7: out0 = f2bf(resid_fp32 + c)    EPI 8: outf = bf2f(out1) + c
template<int EPI>
__global__ __launch_bounds__(512, 4)
void gemm_bt(const u16* __restrict__ A, const u16* __restrict__ Bw,
             int M, int N, int K,
             const float* __restrict__ bias0, const float* __restrict__ bias1,
             const float* resid, float* outf,
             u16* __restrict__ out0, u16* __restrict__ out1, int Dsub) {
    __shared__ __align__(16) u16 lA[256 * 64];   // 32 KB
    __shared__ __align__(16) u16 lB[128 * 64];   // 16 KB
    const int tid  = threadIdx.x;
    const int lane = tid & 63;
    const int wave = tid >> 6;                     // 0..7
    const int wr = (wave >> 1) << 6;               // 0/64/128/192
    const int wc = (wave & 1) << 6;                // 0 / 64
    const int brow = blockIdx.x * 256;
    const int bcol = blockIdx.y * 128;

    // staging: 64 rows/issue (512 threads x 16B = 8KB); source chunk pre-swizzled
    const int srow  = tid >> 3;                    // 0..63
    const int schnk = (tid & 7) ^ (srow & 7);      // inverse-swizzle source
    const size_t soff = (size_t)srow * K + (schnk << 3);
    const u16* gA = A  + (size_t)brow * K + soff;
    const u16* gB = Bw + (size_t)bcol * K + soff;
    u16* lAp = lA + tid * 8;                       // linear dest, lane*16B
    u16* lBp = lB + tid * 8;

    // read-address pieces
    const int fr = lane & 15;
    const int lg = lane >> 4;                      // 0..3
    const int ck0 = ((lg)     ^ (fr & 7)) << 4;    // k-half 0 chunk byte
    const int ck1 = ((4 + lg) ^ (fr & 7)) << 4;    // k-half 1 chunk byte
    const char* lAc = (const char*)lA;
    const char* lBc = (const char*)lB;

    f32x4 acc[4][4];
#pragma unroll
    for (int i = 0; i < 4; ++i)
#pragma unroll
        for (int j = 0; j < 4; ++j)
            acc[i][j] = (f32x4){0.f, 0.f, 0.f, 0.f};

    for (int k0 = 0; k0 < K; k0 += 64) {
#pragma unroll
        for (int s = 0; s < 4; ++s)
            gload16(gA + k0 + (size_t)s * 64 * K, lAp + s * 4096);
#pragma unroll
        for (int s = 0; s < 2; ++s)
            gload16(gB + k0 + (size_t)s * 64 * K, lBp + s * 4096);
        __syncthreads();
        s16x8 bq[4][2];
#pragma unroll
        for (int j = 0; j < 4; ++j) {
            const int rb = (wc + j * 16 + fr) * 128;
            bq[j][0] = *(const s16x8*)(lBc + rb + ck0);
            bq[j][1] = *(const s16x8*)(lBc + rb + ck1);
        }
#pragma unroll
        for (int i = 0; i < 4; ++i) {
            const int ra = (wr + i * 16 + fr) * 128;
            s16x8 a0 = *(const s16x8*)(lAc + ra + ck0);
            s16x8 a1 = *(const s16x8*)(lAc + ra + ck1);
#pragma unroll
            for (int j = 0; j < 4; ++j) {
                mfma16(acc[i][j], a0, bq[j][0]);
                mfma16(acc[i][j], a1, bq[j][1]);
            }
        }
        __syncthreads();
    }

    // MFMA-write -> VALU-read hazard fence
#pragma unroll
    for (int i = 0; i < 4; ++i)
#pragma unroll
        for (int j = 0; j < 4; ++j)
            asm volatile("s_nop 7" : "+v"(acc[i][j]));

    const int r0 = brow + wr + (lg << 2);

    if (EPI == 3 || (EPI == 6 && bcol < 2 * DD)) {
        // paired epilogue: first acc[i][0..1] pairs with second acc[i][2..3]
        const int nb = bcol >> 7;
        const int cbase = nb * 64 + (wc ? 32 : 0);
#pragma unroll
        for (int i = 0; i < 4; ++i)
#pragma unroll
            for (int j = 0; j < 2; ++j)
#pragma unroll
                for (int e = 0; e < 4; ++e) {
                    const int grow = r0 + i * 16 + e;
                    const int col  = cbase + j * 16 + fr;
                    const float g = acc[i][j][e];
                    const float u = acc[i][j + 2][e];
                    float v;
                    if (EPI == 3) v = g * sigm(g) * u;           // silu(gate)*up
                    else          v = sigm(g + bias0[col]) * u;  // sigmoid(r+br)*xp
                    out0[(size_t)grow * Dsub + col] = f2bf(v);
                }
        return;
    }

    const int c0 = bcol + wc + fr;
#pragma unroll
    for (int i = 0; i < 4; ++i) {
#pragma unroll
        for (int j = 0; j < 4; ++j) {
            const int gcol = c0 + j * 16;
#pragma unroll
            for (int e = 0; e < 4; ++e) {
                const int grow = r0 + i * 16 + e;
                float c = acc[i][j][e];
                if (EPI == 7) {
                    const size_t idx = (size_t)grow * N + gcol;
                    out0[idx] = f2bf(resid[idx] + c);
                } else if (EPI == 8) {
                    const size_t idx = (size_t)grow * N + gcol;
                    outf[idx] = bf2f(out1[idx]) + c;
                } else {  // EPI == 6, g branch: cols offset by 2*DD
                    const int gc = gcol - 2 * DD;
                    out1[(size_t)grow * Dsub + gc] = f2bf(sigm(c + bias1[gc]));
                }
            }
        }
    }
}

// ================= chunked RG-LRU scan (3 passes, x4 vectorized) =================
// BP = sigmoid(r+b_r)*xp from the EPI6 GEMM; b_t = sc * BP.
__global__ __launch_bounds__(256)
void scan_partial(const u16x4* __restrict__ BP4,
                  const float4* __restrict__ ld4, float4* __restrict__ carry4) {
    const int d4 = blockIdx.x * 256 + threadIdx.x;   // channel-group (4 ch)
    const int k = blockIdx.y;
    const int b = blockIdx.z;
    const float4 ld = ld4[d4];
    float a[4], sc[4], h[4];
#pragma unroll
    for (int c = 0; c < 4; ++c) {
        float av = sigm(((const float*)&ld)[c]);
        av = fminf(fmaxf(av, 1e-6f), 1.f - 1e-6f);
        a[c] = av; sc[c] = sqrtf(fmaxf(1.f - av * av, 0.f)); h[c] = 0.f;
    }
    size_t idx = (((size_t)b * TD + (size_t)k * CHL) * DD >> 2) + d4;
#pragma unroll 8
    for (int t = 0; t < CHL; ++t) {
        u16x4 bp = BP4[idx];
#pragma unroll
        for (int c = 0; c < 4; ++c) h[c] = a[c] * h[c] + sc[c] * bf2f(bp[c]);
        idx += DD >> 2;
    }
    float4 o = { h[0], h[1], h[2], h[3] };
    carry4[(((size_t)b * CHK + k) * DD >> 2) + d4] = o;
}

// exclusive prefix over chunk carries -> carryin; also emits hfin (exact)
__global__ __launch_bounds__(256)
void scan_carry(const float4* __restrict__ state4, const float4* __restrict__ ld4,
                const float4* __restrict__ carry4, float4* __restrict__ carryin4,
                float4* __restrict__ hfin4) {
    const int d4 = blockIdx.x * 256 + threadIdx.x;
    const int b = blockIdx.y;
    const float4 ld = ld4[d4];
    float aL[4], h[4];
    const float4 st = state4[((size_t)b * DD >> 2) + d4];
#pragma unroll
    for (int c = 0; c < 4; ++c) {
        float av = sigm(((const float*)&ld)[c]);
        av = fminf(fmaxf(av, 1e-6f), 1.f - 1e-6f);
        float p = av;
#pragma unroll
        for (int i = 0; i < 6; ++i) p *= p;   // a^64 == a^CHL
        aL[c] = p;
        h[c] = ((const float*)&st)[c];
    }
#pragma unroll
    for (int k = 0; k < CHK; ++k) {
        const size_t ci = (((size_t)b * CHK + k) * DD >> 2) + d4;
        float4 o = { h[0], h[1], h[2], h[3] };
        carryin4[ci] = o;
        float4 cv = carry4[ci];
#pragma unroll
        for (int c = 0; c < 4; ++c) h[c] = aL[c] * h[c] + ((const float*)&cv)[c];
    }
    float4 o = { h[0], h[1], h[2], h[3] };
    hfin4[((size_t)b * DD >> 2) + d4] = o;
}

// final pass: true chunk-entry state; emits hsg
__global__ __launch_bounds__(256)
void scan_final(const u16x4* __restrict__ BP4, const u16x4* __restrict__ G4,
                const float4* __restrict__ ld4, const float4* __restrict__ carryin4,
                u16x4* __restrict__ HSG4) {
    const int d4 = blockIdx.x * 256 + threadIdx.x;
    const int k = blockIdx.y;
    const int b = blockIdx.z;
    const float4 ld = ld4[d4];
    float a[4], sc[4], h[4];
    const float4 ci = carryin4[(((size_t)b * CHK + k) * DD >> 2) + d4];
#pragma unroll
    for (int c = 0; c < 4; ++c) {
        float av = sigm(((const float*)&ld)[c]);
        av = fminf(fmaxf(av, 1e-6f), 1.f - 1e-6f);
        a[c] = av; sc[c] = sqrtf(fmaxf(1.f - av * av, 0.f));
        h[c] = ((const float*)&ci)[c];
    }
    size_t idx = (((size_t)b * TD + (size_t)k * CHL) * DD >> 2) + d4;
#pragma unroll 8
    for (int t = 0; t < CHL; ++t) {
        u16x4 bp = BP4[idx];
        u16x4 gv = G4[idx];
        u16x4 o;
#pragma unroll
        for (int c = 0; c < 4; ++c) {
            h[c] = a[c] * h[c] + sc[c] * bf2f(bp[c]);
            o[c] = f2bf(h[c] * bf2f(gv[c]));
        }
        HSG4[idx] = o;
        idx += DD >> 2;
    }
}

extern "C" void kernel_launch(void* const* d_in, const int* in_sizes, int n_in,
                              void* d_out, int out_size, void* d_ws, size_t ws_size,
                              hipStream_t stream) {
    const float* x       = (const float*)d_in[0];
    const float* state   = (const float*)d_in[1];
    const float* w_norm1 = (const float*)d_in[2];
    const float* W_in    = (const float*)d_in[3];
    const float* W_r     = (const float*)d_in[4];
    const float* b_r     = (const float*)d_in[5];
    const float* W_i     = (const float*)d_in[6];
    const float* b_i     = (const float*)d_in[7];
    const float* log_dec = (const float*)d_in[8];
    const float* W_out   = (const float*)d_in[9];
    const float* w_norm2 = (const float*)d_in[10];
    const float* W_gate  = (const float*)d_in[11];
    const float* W_up    = (const float*)d_in[12];
    const float* W_down  = (const float*)d_in[13];

    float* out  = (float*)d_out;
    float* hfin = out + (size_t)MD * DD;

    const size_t SEGU = (size_t)DD * DD;                    // u16 elems per D*D
    u16* w_rx    = (u16*)d_ws;                              // [W_r/W_in ilv; W_i] = stacked mixer B
    u16* w_out   = w_rx   + 3 * SEGU;                       // W_out
    u16* w_gu    = w_rx   + 4 * SEGU;                       // [gate/up interleave] 4*SEG
    u16* w_down  = w_rx   + 8 * SEGU;                       // W_down 2*SEG
    u16* bufN    = w_rx   + 10 * SEGU;                      // M*D
    u16* bufBP   = bufN   + (size_t)MD * DD;                // M*D (bP; later act M*DI spans bufBP+bufG)
    u16* bufG    = bufBP  + (size_t)MD * DD;                // M*D
    u16* bufX2   = bufG   + (size_t)MD * DD;                // M*D (x2 bf16)
    float* carry   = (float*)(bufX2 + (size_t)MD * DD);     // B*CHK*D fp32 (1 MB)
    float* carryin = carry + (size_t)BD * CHK * DD;         // B*CHK*D fp32 (1 MB)

    // 1) fused weight converts (r/in and gate/up 32-row interleaved)
    cvt_all<<<2048, 256, 0, stream>>>((const float4*)W_r, (const float4*)W_in,
                                      (const float4*)W_i, (const float4*)W_out,
                                      (const float4*)W_gate, (const float4*)W_up,
                                      (const float4*)W_down, (u16x4*)w_rx,
                                      (int)(10 * SEGU / 4));

    rmsnorm_kernel<<<MD, 256, 0, stream>>>(x, w_norm1, bufN);

    // merged mixer projections: bP (paired rx) + g (W_i), stacked N=6144
    {
        dim3 g1(MD / 256, (3 * DD) / 128);
        gemm_bt<6><<<g1, 512, 0, stream>>>(bufN, w_rx, MD, 3 * DD, DD,
                                           b_r, b_i, nullptr, nullptr, bufBP, bufG, DD);
    }

    // chunked RG-LRU scan (3 passes, x4 vectorized)
    {
        dim3 gp(DD / 1024, CHK, BD);
        scan_partial<<<gp, 256, 0, stream>>>((const u16x4*)bufBP,
                                             (const float4*)log_dec, (float4*)carry);
        dim3 gc(DD / 1024, BD);
        scan_carry<<<gc, 256, 0, stream>>>((const float4*)state, (const float4*)log_dec,
                                           (const float4*)carry, (float4*)carryin,
                                           (float4*)hfin);
        scan_final<<<gp, 256, 0, stream>>>((const u16x4*)bufBP, (const u16x4*)bufG,
                                           (const float4*)log_dec, (const float4*)carryin,
                                           (u16x4*)bufN);
    }

    // x2 = x + hsg @ W_out^T  (bf16, never output directly)
    {
        dim3 g2(MD / 256, DD / 128);
        gemm_bt<7><<<g2, 512, 0, stream>>>(bufN, w_out, MD, DD, DD,
                                           nullptr, nullptr, x, nullptr, bufX2, nullptr, 0);
    }

    rmsnorm_bf16<<<MD, 256, 0, stream>>>(bufX2, w_norm2, bufN);

    // fused gate/up + GLU: stacked N=8192, writes act (M x DI) directly
    {
        dim3 g3(MD / 256, (2 * DID) / 128);
        gemm_bt<3><<<g3, 512, 0, stream>>>(bufN, w_gu, MD, 2 * DID, DD,
                                           nullptr, nullptr, nullptr, nullptr, bufBP, nullptr, DID);
    }

    // out = bf2f(x2) + act @ W_down^T  (fp32 final)
    {
        dim3 g4(MD / 256, DD / 128);
        gemm_bt<8><<<g4, 512, 0, stream>>>(bufBP, w_down, MD, DD, DID,
                                           nullptr, nullptr, nullptr, out, nullptr, bufX2, 0);
    }
}